// Round 16
// baseline (172.088 us; speedup 1.0000x reference)
//
#include <hip/hip_runtime.h>
#include <math.h>

namespace {

constexpr int B    = 128;
constexpr int H    = 1024;
constexpr int V    = 32000;
constexpr int WSZ  = 10;
constexpr int MAXW = 2 * WSZ + 1;   // 21

typedef __attribute__((ext_vector_type(8))) short bf16x8;
typedef __attribute__((ext_vector_type(4))) short short4v;
typedef __attribute__((ext_vector_type(4))) float f32x4;

__device__ __forceinline__ float sigf(float x) { return 1.0f / (1.0f + expf(-x)); }

__device__ __forceinline__ unsigned short rnebf(float f) {
    unsigned u = __float_as_uint(f);
    u += 0x7fffu + ((u >> 16) & 1u);
    return (unsigned short)(u >> 16);
}

__device__ __forceinline__ bf16x8 cvt8(const f32x4 a, const f32x4 b) {
    bf16x8 r;
    r[0] = (short)rnebf(a.x); r[1] = (short)rnebf(a.y);
    r[2] = (short)rnebf(a.z); r[3] = (short)rnebf(a.w);
    r[4] = (short)rnebf(b.x); r[5] = (short)rnebf(b.y);
    r[6] = (short)rnebf(b.z); r[7] = (short)rnebf(b.w);
    return r;
}

// async 16B global -> LDS (gfx950 global_load_lds dwordx4)
// dest must be wave-uniform base; HW adds lane*16.
__device__ __forceinline__ void gl_lds16(const float* g, float* l) {
    __builtin_amdgcn_global_load_lds(
        (const __attribute__((address_space(1))) unsigned int*)g,
        (__attribute__((address_space(3))) unsigned int*)l,
        16, 0, 0);
}

struct S3 { short h, m, l; };

// exact 3-way truncation split: x == h + m + l + delta, |delta| <~ 2^-24 |x|
__device__ __forceinline__ S3 split3(float x) {
    S3 r;
    const unsigned uh = __float_as_uint(x) & 0xFFFF0000u;
    const float fh = __uint_as_float(uh);
    const float r1 = x - fh;
    const unsigned um = __float_as_uint(r1) & 0xFFFF0000u;
    const float fm = __uint_as_float(um);
    const float r2 = r1 - fm;
    const unsigned ul = __float_as_uint(r2) & 0xFFFF0000u;
    r.h = (short)(uh >> 16);
    r.m = (short)(um >> 16);
    r.l = (short)(ul >> 16);
    return r;
}

__device__ __forceinline__ void split8(const f32x4 a, const f32x4 b,
                                       bf16x8& wh, bf16x8& wm, bf16x8& wl) {
    S3 s;
    s = split3(a.x); wh[0] = s.h; wm[0] = s.m; wl[0] = s.l;
    s = split3(a.y); wh[1] = s.h; wm[1] = s.m; wl[1] = s.l;
    s = split3(a.z); wh[2] = s.h; wm[2] = s.m; wl[2] = s.l;
    s = split3(a.w); wh[3] = s.h; wm[3] = s.m; wl[3] = s.l;
    s = split3(b.x); wh[4] = s.h; wm[4] = s.m; wl[4] = s.l;
    s = split3(b.y); wh[5] = s.h; wm[5] = s.m; wl[5] = s.l;
    s = split3(b.z); wh[6] = s.h; wm[6] = s.m; wl[6] = s.l;
    s = split3(b.w); wh[7] = s.h; wm[7] = s.m; wl[7] = s.l;
}

// ---------------------------------------------------------------------------
// LSTM split3 GEMM, row-sequential staged W (unchanged, proven).
// ---------------------------------------------------------------------------
__global__ __launch_bounds__(256, 2) void lstm_gemm(
    const short* __restrict__ Ah0, const short* __restrict__ Am0, const short* __restrict__ Al0,
    const short* __restrict__ Ah1, const short* __restrict__ Am1, const short* __restrict__ Al1,
    const float* __restrict__ W0, const float* __restrict__ W1,
    float* __restrict__ outbase)
{
    __shared__ float wt[2][4160];   // 2 x (16 rows x 260 f32)

    const int t    = threadIdx.x;
    const int lane = t & 63;
    const int w    = t >> 6;
    const int m16  = lane & 15;
    const int g    = lane >> 4;
    const int n0   = blockIdx.x * 64;
    const int y    = blockIdx.y;
    const int src  = y >> 2;
    const int k0   = (y & 3) * 256;
    const short* Ah = src ? Ah1 : Ah0;
    const short* Am = src ? Am1 : Am0;
    const short* Al = src ? Al1 : Al0;
    const float* W  = src ? W1  : W0;
    float* out = outbase + (size_t)y * 128 * 4096;

    bf16x8 ah[2][8], am[2][8], al[2][8];
    #pragma unroll
    for (int q = 0; q < 2; ++q) {
        const size_t ao = (size_t)((w * 2 + q) * 16 + m16) * 1024 + k0 + g * 8;
        #pragma unroll
        for (int s = 0; s < 8; ++s) {
            ah[q][s] = *(const bf16x8*)(Ah + ao + s * 32);
            am[q][s] = *(const bf16x8*)(Am + ao + s * 32);
            al[q][s] = *(const bf16x8*)(Al + ao + s * 32);
        }
    }

#define LSTM_STAGE(BUF, C)                                                  \
    {                                                                       \
        _Pragma("unroll")                                                   \
        for (int i = 0; i < 5; ++i) {                                       \
            const int idx = i * 256 + t;                                    \
            const int rr  = idx / 65;                                       \
            const int pp  = idx - rr * 65;                                  \
            if (idx < 1040 && pp < 64) {                                    \
                const float* s_ = W + (size_t)(n0 + (C) * 16 + rr) * 1024   \
                                + k0 + pp * 4;                              \
                gl_lds16(s_, &wt[BUF][(size_t)(i * 256 + w * 64) * 4]);     \
            }                                                               \
        }                                                                   \
    }

    LSTM_STAGE(0, 0)
    int cur = 0;
    #pragma unroll
    for (int c = 0; c < 4; ++c) {
        __syncthreads();
        if (c < 3) {
            if (cur == 0) LSTM_STAGE(1, c + 1)
            else          LSTM_STAGE(0, c + 1)
        }
        f32x4 acc0 = {}, acc1 = {};
        const float* lrow = &wt[cur][m16 * 260 + g * 8];
        #pragma unroll
        for (int s = 0; s < 8; ++s) {
            const f32x4 wa = *(const f32x4*)(lrow + s * 32);
            const f32x4 wb = *(const f32x4*)(lrow + s * 32 + 4);
            bf16x8 wh, wm, wl;
            split8(wa, wb, wh, wm, wl);
            acc0 = __builtin_amdgcn_mfma_f32_16x16x32_bf16(ah[0][s], wh, acc0, 0, 0, 0);
            acc0 = __builtin_amdgcn_mfma_f32_16x16x32_bf16(ah[0][s], wm, acc0, 0, 0, 0);
            acc0 = __builtin_amdgcn_mfma_f32_16x16x32_bf16(am[0][s], wh, acc0, 0, 0, 0);
            acc0 = __builtin_amdgcn_mfma_f32_16x16x32_bf16(ah[0][s], wl, acc0, 0, 0, 0);
            acc0 = __builtin_amdgcn_mfma_f32_16x16x32_bf16(am[0][s], wm, acc0, 0, 0, 0);
            acc0 = __builtin_amdgcn_mfma_f32_16x16x32_bf16(al[0][s], wh, acc0, 0, 0, 0);
            acc1 = __builtin_amdgcn_mfma_f32_16x16x32_bf16(ah[1][s], wh, acc1, 0, 0, 0);
            acc1 = __builtin_amdgcn_mfma_f32_16x16x32_bf16(ah[1][s], wm, acc1, 0, 0, 0);
            acc1 = __builtin_amdgcn_mfma_f32_16x16x32_bf16(am[1][s], wh, acc1, 0, 0, 0);
            acc1 = __builtin_amdgcn_mfma_f32_16x16x32_bf16(ah[1][s], wl, acc1, 0, 0, 0);
            acc1 = __builtin_amdgcn_mfma_f32_16x16x32_bf16(am[1][s], wm, acc1, 0, 0, 0);
            acc1 = __builtin_amdgcn_mfma_f32_16x16x32_bf16(al[1][s], wh, acc1, 0, 0, 0);
        }
        const int col = n0 + c * 16 + m16;
        #pragma unroll
        for (int j = 0; j < 4; ++j) {
            out[(size_t)(w * 32 + g * 4 + j) * 4096 + col]      = acc0[j];
            out[(size_t)(w * 32 + 16 + g * 4 + j) * 4096 + col] = acc1[j];
        }
        cur ^= 1;
    }
#undef LSTM_STAGE
}

// ---------------------------------------------------------------------------
// fc2 v4: full-K direct write, k-half OUTER / row-group inner.
// y[128 x 32000] = A(bf16 128x1024) @ W^T + bias. Grid (500).
// acc[4][2] persists across k-halves; A reloaded per k-half (<=64 VGPR live).
// Staging identical to the proven round-13 template.
// ---------------------------------------------------------------------------
__global__ __launch_bounds__(256) void fc2_gemm(
    const short* __restrict__ A, const float* __restrict__ W,
    const float* __restrict__ bias, float* __restrict__ out)
{
    __shared__ float wt[2][16 * 516];   // 2 x 33024 B

    const int t    = threadIdx.x;
    const int lane = t & 63;
    const int w    = t >> 6;
    const int m16  = lane & 15;
    const int g    = lane >> 4;
    const int n0   = blockIdx.x * 64;

    f32x4 acc[4][2] = {};

#define FC2_STAGE(BUF, KH, C)                                               \
    {                                                                       \
        _Pragma("unroll")                                                   \
        for (int i = 0; i < 9; ++i) {                                       \
            const int idx = i * 256 + t;                                    \
            const int rr  = idx / 129;                                      \
            const int pp  = idx - rr * 129;                                 \
            if (idx < 2064 && pp < 128) {                                   \
                const float* src = W + (size_t)(n0 + (C) * 16 + rr) * 1024  \
                                 + (KH) * 512 + pp * 4;                     \
                gl_lds16(src, &wt[BUF][(size_t)(i * 256 + w * 64) * 4]);    \
            }                                                               \
        }                                                                   \
    }

    FC2_STAGE(0, 0, 0)
    int cur = 0;
    #pragma unroll
    for (int kh = 0; kh < 2; ++kh) {
        // A preload for this k-half (64 VGPR)
        bf16x8 a[2][16];
        #pragma unroll
        for (int q = 0; q < 2; ++q) {
            const short* ap = A + (size_t)((w * 2 + q) * 16 + m16) * 1024
                            + kh * 512 + g * 8;
            #pragma unroll
            for (int s = 0; s < 16; ++s)
                a[q][s] = *(const bf16x8*)(ap + s * 32);
        }
        #pragma unroll
        for (int c = 0; c < 4; ++c) {
            __syncthreads();                   // wt[cur] staged
            if (c < 3) {
                if (cur == 0) FC2_STAGE(1, kh, c + 1)
                else          FC2_STAGE(0, kh, c + 1)
            } else if (kh == 0) {
                if (cur == 0) FC2_STAGE(1, 1, 0)
                else          FC2_STAGE(0, 1, 0)
            }
            const float* lrow = &wt[cur][m16 * 516 + g * 8];
            #pragma unroll
            for (int s = 0; s < 16; ++s) {
                const f32x4 wa = *(const f32x4*)(lrow + s * 32);
                const f32x4 wb = *(const f32x4*)(lrow + s * 32 + 4);
                const bf16x8 bfr = cvt8(wa, wb);
                acc[c][0] = __builtin_amdgcn_mfma_f32_16x16x32_bf16(a[0][s], bfr, acc[c][0], 0, 0, 0);
                acc[c][1] = __builtin_amdgcn_mfma_f32_16x16x32_bf16(a[1][s], bfr, acc[c][1], 0, 0, 0);
            }
            cur ^= 1;
        }
    }
#undef FC2_STAGE

    #pragma unroll
    for (int c = 0; c < 4; ++c) {
        const int col = n0 + c * 16 + m16;
        const float bv = bias[col];
        #pragma unroll
        for (int j = 0; j < 4; ++j) {
            out[(size_t)(w * 32 + g * 4 + j) * V + col]      = acc[c][0][j] + bv;
            out[(size_t)(w * 32 + 16 + g * 4 + j) * V + col] = acc[c][1][j] + bv;
        }
    }
}

// ---------------------------------------------------------------------------
// Split-bf16 MFMA GEMM (register W prefetch) — kept for the small attn t1pre.
// ---------------------------------------------------------------------------
__global__ __launch_bounds__(256, 2) void gemm_x3(
    const short* __restrict__ Ah0, const short* __restrict__ Am0, const short* __restrict__ Al0,
    const short* __restrict__ Ah1, const short* __restrict__ Am1, const short* __restrict__ Al1,
    const float* __restrict__ W0, const float* __restrict__ W1,
    int N, int Ksz, int ks_log2, float* __restrict__ outbase)
{
    const int y = blockIdx.y;
    const int src = y >> ks_log2;
    const short* Ah = src ? Ah1 : Ah0;
    const short* Am = src ? Am1 : Am0;
    const short* Al = src ? Al1 : Al0;
    const float* W  = src ? W1  : W0;
    const int k0 = (y & ((1 << ks_log2) - 1)) * Ksz;
    float* out = outbase + (size_t)y * 128 * N;

    const int t    = threadIdx.x;
    const int lane = t & 63;
    const int wv   = t >> 6;
    const int n0   = blockIdx.x * 64 + wv * 16;
    const int m16  = lane & 15;
    const int ko8  = (lane >> 4) * 8;

    const float* wp = W + (size_t)(n0 + m16) * 1024 + k0 + ko8;
    const size_t a0 = (size_t)m16 * 1024 + k0 + ko8;

    f32x4 acc[8] = {};

    f32x4 cwa = *(const f32x4*)(wp);      f32x4 cwb = *(const f32x4*)(wp + 4);
    f32x4 nwa = *(const f32x4*)(wp + 32); f32x4 nwb = *(const f32x4*)(wp + 36);

    for (int kc = 0; kc + 64 < Ksz; kc += 32) {
        bf16x8 ah[8], am[8], al[8];
        #pragma unroll
        for (int m = 0; m < 8; ++m) {
            const size_t ao = a0 + (size_t)m * 16384 + kc;
            ah[m] = *(const bf16x8*)(Ah + ao);
            am[m] = *(const bf16x8*)(Am + ao);
            al[m] = *(const bf16x8*)(Al + ao);
        }
        __builtin_amdgcn_sched_barrier(0);
        const f32x4 fwa = *(const f32x4*)(wp + kc + 64);
        const f32x4 fwb = *(const f32x4*)(wp + kc + 68);
        bf16x8 wh, wm, wl;
        split8(cwa, cwb, wh, wm, wl);
        #pragma unroll
        for (int m = 0; m < 8; ++m) {
            acc[m] = __builtin_amdgcn_mfma_f32_16x16x32_bf16(ah[m], wh, acc[m], 0, 0, 0);
            acc[m] = __builtin_amdgcn_mfma_f32_16x16x32_bf16(ah[m], wm, acc[m], 0, 0, 0);
            acc[m] = __builtin_amdgcn_mfma_f32_16x16x32_bf16(am[m], wh, acc[m], 0, 0, 0);
            acc[m] = __builtin_amdgcn_mfma_f32_16x16x32_bf16(ah[m], wl, acc[m], 0, 0, 0);
            acc[m] = __builtin_amdgcn_mfma_f32_16x16x32_bf16(am[m], wm, acc[m], 0, 0, 0);
            acc[m] = __builtin_amdgcn_mfma_f32_16x16x32_bf16(al[m], wh, acc[m], 0, 0, 0);
        }
        cwa = nwa; cwb = nwb; nwa = fwa; nwb = fwb;
    }
    #pragma unroll
    for (int tail = 0; tail < 2; ++tail) {
        const int kc = Ksz - 64 + tail * 32;
        bf16x8 ah[8], am[8], al[8];
        #pragma unroll
        for (int m = 0; m < 8; ++m) {
            const size_t ao = a0 + (size_t)m * 16384 + kc;
            ah[m] = *(const bf16x8*)(Ah + ao);
            am[m] = *(const bf16x8*)(Am + ao);
            al[m] = *(const bf16x8*)(Al + ao);
        }
        const f32x4 wa = tail ? nwa : cwa;
        const f32x4 wb = tail ? nwb : cwb;
        bf16x8 wh, wm, wl;
        split8(wa, wb, wh, wm, wl);
        #pragma unroll
        for (int m = 0; m < 8; ++m) {
            acc[m] = __builtin_amdgcn_mfma_f32_16x16x32_bf16(ah[m], wh, acc[m], 0, 0, 0);
            acc[m] = __builtin_amdgcn_mfma_f32_16x16x32_bf16(ah[m], wm, acc[m], 0, 0, 0);
            acc[m] = __builtin_amdgcn_mfma_f32_16x16x32_bf16(am[m], wh, acc[m], 0, 0, 0);
            acc[m] = __builtin_amdgcn_mfma_f32_16x16x32_bf16(ah[m], wl, acc[m], 0, 0, 0);
            acc[m] = __builtin_amdgcn_mfma_f32_16x16x32_bf16(am[m], wm, acc[m], 0, 0, 0);
            acc[m] = __builtin_amdgcn_mfma_f32_16x16x32_bf16(al[m], wh, acc[m], 0, 0, 0);
        }
    }

    #pragma unroll
    for (int m = 0; m < 8; ++m) {
        const int rbase = m * 16 + (lane >> 4) * 4;
        #pragma unroll
        for (int r = 0; r < 4; ++r)
            out[(size_t)(rbase + r) * N + n0 + m16] = acc[m][r];
    }
}

// ---------------------------------------------------------------------------
// fc1 v2: row-sequential staged W (proven).
// ---------------------------------------------------------------------------
__global__ __launch_bounds__(256, 2) void fc1_gemm(
    const short* __restrict__ A0, const short* __restrict__ A1,
    const float* __restrict__ W, float* __restrict__ outbase)
{
    __shared__ float wt[2][16 * 132];   // 2 x 8448 B

    const int t    = threadIdx.x;
    const int lane = t & 63;
    const int w    = t >> 6;
    const int m16  = lane & 15;
    const int g    = lane >> 4;
    const int n0   = blockIdx.x * 64;
    const int y    = blockIdx.y;
    const int src  = y >> 3;
    const int k0   = (y & 7) * 128;
    const int wk0  = src * 1024 + k0;
    const short* A = src ? A1 : A0;
    float* out = outbase + (size_t)y * 128 * 1024;

    bf16x8 a[2][4];
    #pragma unroll
    for (int q = 0; q < 2; ++q) {
        const short* ap = A + (size_t)((w * 2 + q) * 16 + m16) * 1024 + k0 + g * 8;
        #pragma unroll
        for (int s = 0; s < 4; ++s)
            a[q][s] = *(const bf16x8*)(ap + s * 32);
    }

#define FC1_STAGE(BUF, C)                                                   \
    {                                                                       \
        _Pragma("unroll")                                                   \
        for (int i = 0; i < 3; ++i) {                                       \
            const int idx = i * 256 + t;                                    \
            const int rr  = idx / 33;                                       \
            const int pp  = idx - rr * 33;                                  \
            if (idx < 528 && pp < 32) {                                     \
                const float* s_ = W + (size_t)(n0 + (C) * 16 + rr) * 2048   \
                                + wk0 + pp * 4;                             \
                gl_lds16(s_, &wt[BUF][(size_t)(i * 256 + w * 64) * 4]);     \
            }                                                               \
        }                                                                   \
    }

    FC1_STAGE(0, 0)
    int cur = 0;
    #pragma unroll
    for (int c = 0; c < 4; ++c) {
        __syncthreads();
        if (c < 3) {
            if (cur == 0) FC1_STAGE(1, c + 1)
            else          FC1_STAGE(0, c + 1)
        }
        f32x4 acc0 = {}, acc1 = {};
        const float* lrow = &wt[cur][m16 * 132 + g * 8];
        #pragma unroll
        for (int s = 0; s < 4; ++s) {
            const f32x4 wa = *(const f32x4*)(lrow + s * 32);
            const f32x4 wb = *(const f32x4*)(lrow + s * 32 + 4);
            const bf16x8 bfr = cvt8(wa, wb);
            acc0 = __builtin_amdgcn_mfma_f32_16x16x32_bf16(a[0][s], bfr, acc0, 0, 0, 0);
            acc1 = __builtin_amdgcn_mfma_f32_16x16x32_bf16(a[1][s], bfr, acc1, 0, 0, 0);
        }
        const int col = n0 + c * 16 + m16;
        #pragma unroll
        for (int j = 0; j < 4; ++j) {
            out[(size_t)(w * 32 + g * 4 + j) * 1024 + col]      = acc0[j];
            out[(size_t)(w * 32 + 16 + g * 4 + j) * 1024 + col] = acc1[j];
        }
        cur ^= 1;
    }
#undef FC1_STAGE
}

// ---------------------------------------------------------------------------
// prep: embed lookup + split3 (blocks 0..127) and h0 split3 (blocks 128..383)
__global__ void prep_k(const int* __restrict__ word, const float* __restrict__ emb,
                       const float* __restrict__ h0,
                       short* __restrict__ xh, short* __restrict__ xm, short* __restrict__ xl,
                       short* __restrict__ h0h, short* __restrict__ h0m, short* __restrict__ h0l)
{
    const int blk = blockIdx.x, t = threadIdx.x;
    const float* src; short *dh, *dm, *dl; size_t off;
    if (blk < 128) {
        src = emb + (size_t)word[blk] * H; off = (size_t)blk * H;
        dh = xh; dm = xm; dl = xl;
    } else {
        const int i = blk - 128;
        src = h0 + (size_t)i * H; off = (size_t)i * H;
        dh = h0h; dm = h0m; dl = h0l;
    }
    const float4 v = ((const float4*)src)[t];
    short4v sh, sm, sl;
    S3 s;
    s = split3(v.x); sh.x = s.h; sm.x = s.m; sl.x = s.l;
    s = split3(v.y); sh.y = s.h; sm.y = s.m; sl.y = s.l;
    s = split3(v.z); sh.z = s.h; sm.z = s.m; sl.z = s.l;
    s = split3(v.w); sh.w = s.h; sm.w = s.m; sl.w = s.l;
    *(short4v*)(dh + off + t * 4) = sh;
    *(short4v*)(dm + off + t * 4) = sm;
    *(short4v*)(dl + off + t * 4) = sl;
}

// sum 8 partials + biases -> LSTM cell -> h (fp32), c (fp32), x splits (bf16)
__global__ void lstm_cell_k(const float* __restrict__ part,
                            const float* __restrict__ bih, const float* __restrict__ bhh,
                            const float* __restrict__ c0,
                            float* __restrict__ h_out, float* __restrict__ c_out,
                            short* __restrict__ xh, short* __restrict__ xm,
                            short* __restrict__ xl)
{
    const int idx = blockIdx.x * 256 + threadIdx.x;   // < 128*1024
    const int b = idx >> 10, hh = idx & 1023;
    const size_t base = (size_t)b * 4096;
    float g[4];
    #pragma unroll
    for (int j = 0; j < 4; ++j) {
        const int o = hh + j * H;
        float s = bih[o] + bhh[o];
        #pragma unroll
        for (int i = 0; i < 8; ++i) s += part[base + o + (size_t)i * 524288];
        g[j] = s;
    }
    const float c = sigf(g[1]) * c0[idx] + sigf(g[0]) * tanhf(g[2]);
    const float h = sigf(g[3]) * tanhf(c);
    c_out[idx] = c;
    h_out[idx] = h;
    const S3 s = split3(h);
    xh[idx] = s.h; xm[idx] = s.m; xl[idx] = s.l;
}

// fused: finish p from 16 t1pre partials -> window -> scores -> softmax*gauss
// -> a (out) and ctx (bf16)
__global__ void attn_ctx_k(const float* __restrict__ part, const float* __restrict__ b1,
                           const float* __restrict__ w2v, const float* __restrict__ b2,
                           const int* __restrict__ Sptr,
                           const float* __restrict__ x, const float* __restrict__ enc,
                           float* __restrict__ a_out, short* __restrict__ ctxb)
{
    __shared__ float red[256];
    __shared__ float so[H];
    __shared__ float swred[4][MAXW];
    __shared__ float ssc[MAXW];
    __shared__ float sa[MAXW];
    __shared__ float sp;
    __shared__ int sw0, sw1;
    const int b = blockIdx.x, t = threadIdx.x;
    const int lane = t & 63, wvv = t >> 6;

    {
        const float* pa = part + (size_t)b * 512;
        float v = 0.f;
        #pragma unroll
        for (int jj = 0; jj < 2; ++jj) {
            const int j = t + jj * 256;
            float sgm = b1[j];
            #pragma unroll
            for (int i = 0; i < 16; ++i) sgm += pa[j + (size_t)i * 65536];
            v += tanhf(sgm) * w2v[j];
        }
        red[t] = v;
        __syncthreads();
        for (int s = 128; s > 0; s >>= 1) {
            if (t < s) red[t] += red[t + s];
            __syncthreads();
        }
        if (t == 0) {
            const float S = (float)Sptr[0];
            const float sv = S * sigf(red[0] + b2[0]);
            sp  = sv;
            sw0 = (int)rintf(fmaxf(sv - (float)WSZ, 0.f));
            sw1 = (int)rintf(fminf(sv + (float)WSZ, S - 1.f));
        }
    }
    for (int h = t; h < H; h += 256) so[h] = x[(size_t)b * H + h];
    __syncthreads();
    const int w0 = sw0, w1e = sw1;
    const float pbv = sp;

    float ps[MAXW];
    #pragma unroll
    for (int w = 0; w < MAXW; ++w) ps[w] = 0.f;
    for (int h4 = t; h4 < H / 4; h4 += 256) {
        const float4 o = ((const float4*)so)[h4];
        #pragma unroll
        for (int w = 0; w < MAXW; ++w) {
            const int idx = w0 + w;
            if (idx <= w1e) {
                const float4 e = *(const float4*)(enc + ((size_t)idx * B + b) * H + h4 * 4);
                ps[w] += o.x * e.x + o.y * e.y + o.z * e.z + o.w * e.w;
            }
        }
    }
    #pragma unroll
    for (int w = 0; w < MAXW; ++w) {
        float v = ps[w];
        for (int off = 32; off > 0; off >>= 1) v += __shfl_down(v, off);
        if (lane == 0) swred[wvv][w] = v;
    }
    __syncthreads();
    if (t == 0) {
        float m = -1e30f;
        for (int w = 0; w < MAXW; ++w) {
            const float s = swred[0][w] + swred[1][w] + swred[2][w] + swred[3][w];
            ssc[w] = s;
            m = fmaxf(m, s);
        }
        float den = 0.f;
        for (int w = 0; w < MAXW; ++w) den += expf(ssc[w] - m);
        for (int w = 0; w < MAXW; ++w) {
            const int idx = w0 + w;
            const float gauss = (idx <= w1e) ? expf(((float)idx - pbv) / 50.0f) : 0.f;
            sa[w] = expf(ssc[w] - m) / den * gauss;
        }
    }
    __syncthreads();
    if (t < MAXW) a_out[b * MAXW + t] = sa[t];
    for (int h4 = t; h4 < H / 4; h4 += 256) {
        float4 acc = {0.f, 0.f, 0.f, 0.f};
        #pragma unroll
        for (int w = 0; w < MAXW; ++w) {
            const int idx = w0 + w;
            if (idx <= w1e) {
                const float4 e = *(const float4*)(enc + ((size_t)idx * B + b) * H + h4 * 4);
                acc.x += sa[w] * e.x; acc.y += sa[w] * e.y;
                acc.z += sa[w] * e.z; acc.w += sa[w] * e.w;
            }
        }
        short4v s;
        s.x = (short)rnebf(acc.x); s.y = (short)rnebf(acc.y);
        s.z = (short)rnebf(acc.z); s.w = (short)rnebf(acc.w);
        *(short4v*)(ctxb + (size_t)b * H + h4 * 4) = s;
    }
}

// sum 16 fc1 partials + bias -> tanh -> o2 (fp32, d_out) + o2b (bf16)
__global__ void fc1_fin_k(const float* __restrict__ part, const float* __restrict__ bias,
                          float* __restrict__ o2, short* __restrict__ o2b)
{
    const int idx = blockIdx.x * 256 + threadIdx.x;   // < 128*1024
    const int n = idx & 1023;
    float v = bias[n];
    #pragma unroll
    for (int i = 0; i < 16; ++i) v += part[idx + (size_t)i * 131072];
    v = tanhf(v);
    o2[idx] = v;
    o2b[idx] = (short)rnebf(v);
}

// in-place log_softmax per row over V (register row cache)
__global__ __launch_bounds__(1024) void lsm_k(float* __restrict__ y)
{
    __shared__ float sm[16], ss[16], slse;
    const int b = blockIdx.x, t = threadIdx.x;
    float* yrow = y + (size_t)b * V;

    f32x4 r[8];
    float m = -1e30f, s = 0.f;
    #pragma unroll
    for (int i = 0; i < 8; ++i) {
        const int v4 = t + i * 1024;
        if (v4 < V / 4) {
            const f32x4 q = ((const f32x4*)yrow)[v4];
            r[i] = q;
            const float mm = fmaxf(fmaxf(q.x, q.y), fmaxf(q.z, q.w));
            if (mm > m) { s *= expf(m - mm); m = mm; }
            s += expf(q.x - m) + expf(q.y - m) + expf(q.z - m) + expf(q.w - m);
        }
    }
    for (int off = 32; off > 0; off >>= 1) {
        const float mo = __shfl_down(m, off), so = __shfl_down(s, off);
        const float mn = fmaxf(m, mo);
        s = s * expf(m - mn) + so * expf(mo - mn);
        m = mn;
    }
    const int wv = t >> 6, lane = t & 63;
    if (lane == 0) { sm[wv] = m; ss[wv] = s; }
    __syncthreads();
    if (t == 0) {
        float M = sm[0], S = ss[0];
        for (int i = 1; i < 16; ++i) {
            const float mn = fmaxf(M, sm[i]);
            S = S * expf(M - mn) + ss[i] * expf(sm[i] - mn);
            M = mn;
        }
        slse = M + logf(S);
    }
    __syncthreads();
    const float lse = slse;
    #pragma unroll
    for (int i = 0; i < 8; ++i) {
        const int v4 = t + i * 1024;
        if (v4 < V / 4) {
            f32x4 q = r[i];
            q.x -= lse; q.y -= lse; q.z -= lse; q.w -= lse;
            ((f32x4*)yrow)[v4] = q;
        }
    }
}

} // namespace

extern "C" void kernel_launch(void* const* d_in, const int* in_sizes, int n_in,
                              void* d_out, int out_size, void* d_ws, size_t ws_size,
                              hipStream_t stream)
{
    const int*   Sp   = (const int*)d_in[0];
    const float* enc  = (const float*)d_in[1];
    const int*   word = (const int*)d_in[2];
    const float* h0   = (const float*)d_in[3];
    const float* c0   = (const float*)d_in[4];
    const float* emb  = (const float*)d_in[5];
    const float* Wih  = (const float*)d_in[6];
    const float* Whh  = (const float*)d_in[7];
    const float* bih  = (const float*)d_in[8];
    const float* bhh  = (const float*)d_in[9];
    const float* aw1  = (const float*)d_in[10];
    const float* ab1  = (const float*)d_in[11];
    const float* aw2  = (const float*)d_in[12];
    const float* ab2  = (const float*)d_in[13];
    const float* f1w  = (const float*)d_in[14];
    const float* f1b  = (const float*)d_in[15];
    const float* f2w  = (const float*)d_in[16];
    const float* f2b  = (const float*)d_in[17];

    float* outp = (float*)d_out;
    float* y    = outp;                       // 128*32000
    float* o2   = y  + (size_t)B * V;         // 128*1024
    float* hN   = o2 + (size_t)B * H;         // 2*128*1024
    float* cN   = hN + 2 * (size_t)B * H;     // 2*128*1024
    float* aO   = cN + 2 * (size_t)B * H;     // 128*21

    char* wsp = (char*)d_ws;
    short* xh   = (short*)wsp;  wsp += (size_t)B * H * 2;
    short* xm   = (short*)wsp;  wsp += (size_t)B * H * 2;
    short* xl   = (short*)wsp;  wsp += (size_t)B * H * 2;
    short* h0h  = (short*)wsp;  wsp += (size_t)2 * B * H * 2;
    short* h0m  = (short*)wsp;  wsp += (size_t)2 * B * H * 2;
    short* h0l  = (short*)wsp;  wsp += (size_t)2 * B * H * 2;
    short* ctxb = (short*)wsp;  wsp += (size_t)B * H * 2;
    short* o2b  = (short*)wsp;  wsp += (size_t)B * H * 2;
    float* part = (float*)wsp;  wsp += (size_t)16 * B * 4 * H * 4;  // 32 MB

    prep_k<<<dim3(384), dim3(256), 0, stream>>>(word, emb, h0, xh, xm, xl, h0h, h0m, h0l);

    for (int l = 0; l < 2; ++l) {
        lstm_gemm<<<dim3(64, 8), dim3(256), 0, stream>>>(
            xh, xm, xl,
            h0h + (size_t)l * B * H, h0m + (size_t)l * B * H, h0l + (size_t)l * B * H,
            Wih + (size_t)l * 4 * H * H, Whh + (size_t)l * 4 * H * H,
            part);
        lstm_cell_k<<<dim3(B * H / 256), dim3(256), 0, stream>>>(
            part, bih + (size_t)l * 4 * H, bhh + (size_t)l * 4 * H,
            c0 + (size_t)l * B * H,
            hN + (size_t)l * B * H, cN + (size_t)l * B * H, xh, xm, xl);
    }

    const float* hfin = hN + (size_t)B * H;  // last layer h (fp32)

    // attn position pre-GEMM: t1pre = h @ w1^T (split3 MFMA, 16 K-partials)
    gemm_x3<<<dim3(8, 16), dim3(256), 0, stream>>>(
        xh, xm, xl, xh, xm, xl, aw1, aw1, 512, 64, 4, part);
    attn_ctx_k<<<dim3(B), dim3(256), 0, stream>>>(
        part, ab1, aw2, ab2, Sp, hfin, enc, aO, ctxb);

    // fc1: [ctx | out] @ f1w^T -> 16 sequential-staged split-K partials -> tanh
    fc1_gemm<<<dim3(16, 16), dim3(256), 0, stream>>>(ctxb, xh, f1w, part);
    fc1_fin_k<<<dim3(B * H / 256), dim3(256), 0, stream>>>(part, f1b, o2, o2b);

    // fc2 v4: full-K direct write (k-half outer, A reload per half)
    fc2_gemm<<<dim3(V / 64), dim3(256), 0, stream>>>(o2b, f2w, f2b, y);

    // in-place log_softmax
    lsm_k<<<dim3(B), dim3(1024), 0, stream>>>(y);
}

// Round 17
// 168.200 us; speedup vs baseline: 1.0231x; 1.0231x over previous
//
#include <hip/hip_runtime.h>
#include <math.h>

namespace {

constexpr int B    = 128;
constexpr int H    = 1024;
constexpr int V    = 32000;
constexpr int WSZ  = 10;
constexpr int MAXW = 2 * WSZ + 1;   // 21

typedef __attribute__((ext_vector_type(8))) short bf16x8;
typedef __attribute__((ext_vector_type(4))) short short4v;
typedef __attribute__((ext_vector_type(4))) float f32x4;

__device__ __forceinline__ float sigf(float x) { return 1.0f / (1.0f + expf(-x)); }

__device__ __forceinline__ unsigned short rnebf(float f) {
    unsigned u = __float_as_uint(f);
    u += 0x7fffu + ((u >> 16) & 1u);
    return (unsigned short)(u >> 16);
}

__device__ __forceinline__ bf16x8 cvt8(const f32x4 a, const f32x4 b) {
    bf16x8 r;
    r[0] = (short)rnebf(a.x); r[1] = (short)rnebf(a.y);
    r[2] = (short)rnebf(a.z); r[3] = (short)rnebf(a.w);
    r[4] = (short)rnebf(b.x); r[5] = (short)rnebf(b.y);
    r[6] = (short)rnebf(b.z); r[7] = (short)rnebf(b.w);
    return r;
}

// async 16B global -> LDS (gfx950 global_load_lds dwordx4)
// dest must be wave-uniform base; HW adds lane*16.
__device__ __forceinline__ void gl_lds16(const float* g, float* l) {
    __builtin_amdgcn_global_load_lds(
        (const __attribute__((address_space(1))) unsigned int*)g,
        (__attribute__((address_space(3))) unsigned int*)l,
        16, 0, 0);
}

struct S3 { short h, m, l; };

// exact 3-way truncation split: x == h + m + l + delta, |delta| <~ 2^-24 |x|
__device__ __forceinline__ S3 split3(float x) {
    S3 r;
    const unsigned uh = __float_as_uint(x) & 0xFFFF0000u;
    const float fh = __uint_as_float(uh);
    const float r1 = x - fh;
    const unsigned um = __float_as_uint(r1) & 0xFFFF0000u;
    const float fm = __uint_as_float(um);
    const float r2 = r1 - fm;
    const unsigned ul = __float_as_uint(r2) & 0xFFFF0000u;
    r.h = (short)(uh >> 16);
    r.m = (short)(um >> 16);
    r.l = (short)(ul >> 16);
    return r;
}

__device__ __forceinline__ void split8(const f32x4 a, const f32x4 b,
                                       bf16x8& wh, bf16x8& wm, bf16x8& wl) {
    S3 s;
    s = split3(a.x); wh[0] = s.h; wm[0] = s.m; wl[0] = s.l;
    s = split3(a.y); wh[1] = s.h; wm[1] = s.m; wl[1] = s.l;
    s = split3(a.z); wh[2] = s.h; wm[2] = s.m; wl[2] = s.l;
    s = split3(a.w); wh[3] = s.h; wm[3] = s.m; wl[3] = s.l;
    s = split3(b.x); wh[4] = s.h; wm[4] = s.m; wl[4] = s.l;
    s = split3(b.y); wh[5] = s.h; wm[5] = s.m; wl[5] = s.l;
    s = split3(b.z); wh[6] = s.h; wm[6] = s.m; wl[6] = s.l;
    s = split3(b.w); wh[7] = s.h; wm[7] = s.m; wl[7] = s.l;
}

// ---------------------------------------------------------------------------
// LSTM split3 GEMM, row-sequential staged W (proven).
// ---------------------------------------------------------------------------
__global__ __launch_bounds__(256, 2) void lstm_gemm(
    const short* __restrict__ Ah0, const short* __restrict__ Am0, const short* __restrict__ Al0,
    const short* __restrict__ Ah1, const short* __restrict__ Am1, const short* __restrict__ Al1,
    const float* __restrict__ W0, const float* __restrict__ W1,
    float* __restrict__ outbase)
{
    __shared__ float wt[2][4160];   // 2 x (16 rows x 260 f32)

    const int t    = threadIdx.x;
    const int lane = t & 63;
    const int w    = t >> 6;
    const int m16  = lane & 15;
    const int g    = lane >> 4;
    const int n0   = blockIdx.x * 64;
    const int y    = blockIdx.y;
    const int src  = y >> 2;
    const int k0   = (y & 3) * 256;
    const short* Ah = src ? Ah1 : Ah0;
    const short* Am = src ? Am1 : Am0;
    const short* Al = src ? Al1 : Al0;
    const float* W  = src ? W1  : W0;
    float* out = outbase + (size_t)y * 128 * 4096;

    bf16x8 ah[2][8], am[2][8], al[2][8];
    #pragma unroll
    for (int q = 0; q < 2; ++q) {
        const size_t ao = (size_t)((w * 2 + q) * 16 + m16) * 1024 + k0 + g * 8;
        #pragma unroll
        for (int s = 0; s < 8; ++s) {
            ah[q][s] = *(const bf16x8*)(Ah + ao + s * 32);
            am[q][s] = *(const bf16x8*)(Am + ao + s * 32);
            al[q][s] = *(const bf16x8*)(Al + ao + s * 32);
        }
    }

#define LSTM_STAGE(BUF, C)                                                  \
    {                                                                       \
        _Pragma("unroll")                                                   \
        for (int i = 0; i < 5; ++i) {                                       \
            const int idx = i * 256 + t;                                    \
            const int rr  = idx / 65;                                       \
            const int pp  = idx - rr * 65;                                  \
            if (idx < 1040 && pp < 64) {                                    \
                const float* s_ = W + (size_t)(n0 + (C) * 16 + rr) * 1024   \
                                + k0 + pp * 4;                              \
                gl_lds16(s_, &wt[BUF][(size_t)(i * 256 + w * 64) * 4]);     \
            }                                                               \
        }                                                                   \
    }

    LSTM_STAGE(0, 0)
    int cur = 0;
    #pragma unroll
    for (int c = 0; c < 4; ++c) {
        __syncthreads();
        if (c < 3) {
            if (cur == 0) LSTM_STAGE(1, c + 1)
            else          LSTM_STAGE(0, c + 1)
        }
        f32x4 acc0 = {}, acc1 = {};
        const float* lrow = &wt[cur][m16 * 260 + g * 8];
        #pragma unroll
        for (int s = 0; s < 8; ++s) {
            const f32x4 wa = *(const f32x4*)(lrow + s * 32);
            const f32x4 wb = *(const f32x4*)(lrow + s * 32 + 4);
            bf16x8 wh, wm, wl;
            split8(wa, wb, wh, wm, wl);
            acc0 = __builtin_amdgcn_mfma_f32_16x16x32_bf16(ah[0][s], wh, acc0, 0, 0, 0);
            acc0 = __builtin_amdgcn_mfma_f32_16x16x32_bf16(ah[0][s], wm, acc0, 0, 0, 0);
            acc0 = __builtin_amdgcn_mfma_f32_16x16x32_bf16(am[0][s], wh, acc0, 0, 0, 0);
            acc0 = __builtin_amdgcn_mfma_f32_16x16x32_bf16(ah[0][s], wl, acc0, 0, 0, 0);
            acc0 = __builtin_amdgcn_mfma_f32_16x16x32_bf16(am[0][s], wm, acc0, 0, 0, 0);
            acc0 = __builtin_amdgcn_mfma_f32_16x16x32_bf16(al[0][s], wh, acc0, 0, 0, 0);
            acc1 = __builtin_amdgcn_mfma_f32_16x16x32_bf16(ah[1][s], wh, acc1, 0, 0, 0);
            acc1 = __builtin_amdgcn_mfma_f32_16x16x32_bf16(ah[1][s], wm, acc1, 0, 0, 0);
            acc1 = __builtin_amdgcn_mfma_f32_16x16x32_bf16(am[1][s], wh, acc1, 0, 0, 0);
            acc1 = __builtin_amdgcn_mfma_f32_16x16x32_bf16(ah[1][s], wl, acc1, 0, 0, 0);
            acc1 = __builtin_amdgcn_mfma_f32_16x16x32_bf16(am[1][s], wm, acc1, 0, 0, 0);
            acc1 = __builtin_amdgcn_mfma_f32_16x16x32_bf16(al[1][s], wh, acc1, 0, 0, 0);
        }
        const int col = n0 + c * 16 + m16;
        #pragma unroll
        for (int j = 0; j < 4; ++j) {
            out[(size_t)(w * 32 + g * 4 + j) * 4096 + col]      = acc0[j];
            out[(size_t)(w * 32 + 16 + g * 4 + j) * 4096 + col] = acc1[j];
        }
        cur ^= 1;
    }
#undef LSTM_STAGE
}

// ---------------------------------------------------------------------------
// fc2 (round-13 proven): split-K, row-sequential staged W, pf2 partials.
// part[y][128 x 32000] = A(bf16 128x[k0:+512]) @ W[:, k0:+512]^T
// ---------------------------------------------------------------------------
__global__ __launch_bounds__(256) void fc2_gemm(
    const short* __restrict__ A, const float* __restrict__ W,
    float* __restrict__ outbase)
{
    __shared__ float wt[2][16 * 516];   // 2 x 33024 B

    const int t    = threadIdx.x;
    const int lane = t & 63;
    const int w    = t >> 6;
    const int m16  = lane & 15;
    const int g    = lane >> 4;
    const int n0   = blockIdx.x * 64;
    const int y    = blockIdx.y;
    const int k0   = y * 512;
    float* out = outbase + (size_t)y * B * V;

    bf16x8 a[2][16];
    #pragma unroll
    for (int q = 0; q < 2; ++q) {
        const short* ap = A + (size_t)((w * 2 + q) * 16 + m16) * 1024 + k0 + g * 8;
        #pragma unroll
        for (int s = 0; s < 16; ++s)
            a[q][s] = *(const bf16x8*)(ap + s * 32);
    }

#define FC2_STAGE(BUF, C)                                                   \
    {                                                                       \
        _Pragma("unroll")                                                   \
        for (int i = 0; i < 9; ++i) {                                       \
            const int idx = i * 256 + t;                                    \
            const int rr  = idx / 129;                                      \
            const int pp  = idx - rr * 129;                                 \
            if (idx < 2064 && pp < 128) {                                   \
                const float* src = W + (size_t)(n0 + (C) * 16 + rr) * 1024  \
                                 + k0 + pp * 4;                             \
                gl_lds16(src, &wt[BUF][(size_t)(i * 256 + w * 64) * 4]);    \
            }                                                               \
        }                                                                   \
    }

    FC2_STAGE(0, 0)
    int cur = 0;
    #pragma unroll
    for (int c = 0; c < 4; ++c) {
        __syncthreads();
        if (c < 3) {
            if (cur == 0) FC2_STAGE(1, c + 1)
            else          FC2_STAGE(0, c + 1)
        }
        f32x4 acc0 = {}, acc1 = {};
        const float* lrow = &wt[cur][m16 * 516 + g * 8];
        #pragma unroll
        for (int s = 0; s < 16; ++s) {
            const f32x4 wa = *(const f32x4*)(lrow + s * 32);
            const f32x4 wb = *(const f32x4*)(lrow + s * 32 + 4);
            const bf16x8 bfr = cvt8(wa, wb);
            acc0 = __builtin_amdgcn_mfma_f32_16x16x32_bf16(a[0][s], bfr, acc0, 0, 0, 0);
            acc1 = __builtin_amdgcn_mfma_f32_16x16x32_bf16(a[1][s], bfr, acc1, 0, 0, 0);
        }
        const int col = n0 + c * 16 + m16;
        #pragma unroll
        for (int j = 0; j < 4; ++j) {
            out[(size_t)(w * 32 + g * 4 + j) * V + col]      = acc0[j];
            out[(size_t)(w * 32 + 16 + g * 4 + j) * V + col] = acc1[j];
        }
        cur ^= 1;
    }
#undef FC2_STAGE
}

// ---------------------------------------------------------------------------
// Split-bf16 MFMA GEMM (register W prefetch) — kept for the small attn t1pre.
// ---------------------------------------------------------------------------
__global__ __launch_bounds__(256, 2) void gemm_x3(
    const short* __restrict__ Ah0, const short* __restrict__ Am0, const short* __restrict__ Al0,
    const short* __restrict__ Ah1, const short* __restrict__ Am1, const short* __restrict__ Al1,
    const float* __restrict__ W0, const float* __restrict__ W1,
    int N, int Ksz, int ks_log2, float* __restrict__ outbase)
{
    const int y = blockIdx.y;
    const int src = y >> ks_log2;
    const short* Ah = src ? Ah1 : Ah0;
    const short* Am = src ? Am1 : Am0;
    const short* Al = src ? Al1 : Al0;
    const float* W  = src ? W1  : W0;
    const int k0 = (y & ((1 << ks_log2) - 1)) * Ksz;
    float* out = outbase + (size_t)y * 128 * N;

    const int t    = threadIdx.x;
    const int lane = t & 63;
    const int wv   = t >> 6;
    const int n0   = blockIdx.x * 64 + wv * 16;
    const int m16  = lane & 15;
    const int ko8  = (lane >> 4) * 8;

    const float* wp = W + (size_t)(n0 + m16) * 1024 + k0 + ko8;
    const size_t a0 = (size_t)m16 * 1024 + k0 + ko8;

    f32x4 acc[8] = {};

    f32x4 cwa = *(const f32x4*)(wp);      f32x4 cwb = *(const f32x4*)(wp + 4);
    f32x4 nwa = *(const f32x4*)(wp + 32); f32x4 nwb = *(const f32x4*)(wp + 36);

    for (int kc = 0; kc + 64 < Ksz; kc += 32) {
        bf16x8 ah[8], am[8], al[8];
        #pragma unroll
        for (int m = 0; m < 8; ++m) {
            const size_t ao = a0 + (size_t)m * 16384 + kc;
            ah[m] = *(const bf16x8*)(Ah + ao);
            am[m] = *(const bf16x8*)(Am + ao);
            al[m] = *(const bf16x8*)(Al + ao);
        }
        __builtin_amdgcn_sched_barrier(0);
        const f32x4 fwa = *(const f32x4*)(wp + kc + 64);
        const f32x4 fwb = *(const f32x4*)(wp + kc + 68);
        bf16x8 wh, wm, wl;
        split8(cwa, cwb, wh, wm, wl);
        #pragma unroll
        for (int m = 0; m < 8; ++m) {
            acc[m] = __builtin_amdgcn_mfma_f32_16x16x32_bf16(ah[m], wh, acc[m], 0, 0, 0);
            acc[m] = __builtin_amdgcn_mfma_f32_16x16x32_bf16(ah[m], wm, acc[m], 0, 0, 0);
            acc[m] = __builtin_amdgcn_mfma_f32_16x16x32_bf16(am[m], wh, acc[m], 0, 0, 0);
            acc[m] = __builtin_amdgcn_mfma_f32_16x16x32_bf16(ah[m], wl, acc[m], 0, 0, 0);
            acc[m] = __builtin_amdgcn_mfma_f32_16x16x32_bf16(am[m], wm, acc[m], 0, 0, 0);
            acc[m] = __builtin_amdgcn_mfma_f32_16x16x32_bf16(al[m], wh, acc[m], 0, 0, 0);
        }
        cwa = nwa; cwb = nwb; nwa = fwa; nwb = fwb;
    }
    #pragma unroll
    for (int tail = 0; tail < 2; ++tail) {
        const int kc = Ksz - 64 + tail * 32;
        bf16x8 ah[8], am[8], al[8];
        #pragma unroll
        for (int m = 0; m < 8; ++m) {
            const size_t ao = a0 + (size_t)m * 16384 + kc;
            ah[m] = *(const bf16x8*)(Ah + ao);
            am[m] = *(const bf16x8*)(Am + ao);
            al[m] = *(const bf16x8*)(Al + ao);
        }
        const f32x4 wa = tail ? nwa : cwa;
        const f32x4 wb = tail ? nwb : cwb;
        bf16x8 wh, wm, wl;
        split8(wa, wb, wh, wm, wl);
        #pragma unroll
        for (int m = 0; m < 8; ++m) {
            acc[m] = __builtin_amdgcn_mfma_f32_16x16x32_bf16(ah[m], wh, acc[m], 0, 0, 0);
            acc[m] = __builtin_amdgcn_mfma_f32_16x16x32_bf16(ah[m], wm, acc[m], 0, 0, 0);
            acc[m] = __builtin_amdgcn_mfma_f32_16x16x32_bf16(am[m], wh, acc[m], 0, 0, 0);
            acc[m] = __builtin_amdgcn_mfma_f32_16x16x32_bf16(ah[m], wl, acc[m], 0, 0, 0);
            acc[m] = __builtin_amdgcn_mfma_f32_16x16x32_bf16(am[m], wm, acc[m], 0, 0, 0);
            acc[m] = __builtin_amdgcn_mfma_f32_16x16x32_bf16(al[m], wh, acc[m], 0, 0, 0);
        }
    }

    #pragma unroll
    for (int m = 0; m < 8; ++m) {
        const int rbase = m * 16 + (lane >> 4) * 4;
        #pragma unroll
        for (int r = 0; r < 4; ++r)
            out[(size_t)(rbase + r) * N + n0 + m16] = acc[m][r];
    }
}

// ---------------------------------------------------------------------------
// fc1 v2: row-sequential staged W (proven).
// ---------------------------------------------------------------------------
__global__ __launch_bounds__(256, 2) void fc1_gemm(
    const short* __restrict__ A0, const short* __restrict__ A1,
    const float* __restrict__ W, float* __restrict__ outbase)
{
    __shared__ float wt[2][16 * 132];   // 2 x 8448 B

    const int t    = threadIdx.x;
    const int lane = t & 63;
    const int w    = t >> 6;
    const int m16  = lane & 15;
    const int g    = lane >> 4;
    const int n0   = blockIdx.x * 64;
    const int y    = blockIdx.y;
    const int src  = y >> 3;
    const int k0   = (y & 7) * 128;
    const int wk0  = src * 1024 + k0;
    const short* A = src ? A1 : A0;
    float* out = outbase + (size_t)y * 128 * 1024;

    bf16x8 a[2][4];
    #pragma unroll
    for (int q = 0; q < 2; ++q) {
        const short* ap = A + (size_t)((w * 2 + q) * 16 + m16) * 1024 + k0 + g * 8;
        #pragma unroll
        for (int s = 0; s < 4; ++s)
            a[q][s] = *(const bf16x8*)(ap + s * 32);
    }

#define FC1_STAGE(BUF, C)                                                   \
    {                                                                       \
        _Pragma("unroll")                                                   \
        for (int i = 0; i < 3; ++i) {                                       \
            const int idx = i * 256 + t;                                    \
            const int rr  = idx / 33;                                       \
            const int pp  = idx - rr * 33;                                  \
            if (idx < 528 && pp < 32) {                                     \
                const float* s_ = W + (size_t)(n0 + (C) * 16 + rr) * 2048   \
                                + wk0 + pp * 4;                             \
                gl_lds16(s_, &wt[BUF][(size_t)(i * 256 + w * 64) * 4]);     \
            }                                                               \
        }                                                                   \
    }

    FC1_STAGE(0, 0)
    int cur = 0;
    #pragma unroll
    for (int c = 0; c < 4; ++c) {
        __syncthreads();
        if (c < 3) {
            if (cur == 0) FC1_STAGE(1, c + 1)
            else          FC1_STAGE(0, c + 1)
        }
        f32x4 acc0 = {}, acc1 = {};
        const float* lrow = &wt[cur][m16 * 132 + g * 8];
        #pragma unroll
        for (int s = 0; s < 4; ++s) {
            const f32x4 wa = *(const f32x4*)(lrow + s * 32);
            const f32x4 wb = *(const f32x4*)(lrow + s * 32 + 4);
            const bf16x8 bfr = cvt8(wa, wb);
            acc0 = __builtin_amdgcn_mfma_f32_16x16x32_bf16(a[0][s], bfr, acc0, 0, 0, 0);
            acc1 = __builtin_amdgcn_mfma_f32_16x16x32_bf16(a[1][s], bfr, acc1, 0, 0, 0);
        }
        const int col = n0 + c * 16 + m16;
        #pragma unroll
        for (int j = 0; j < 4; ++j) {
            out[(size_t)(w * 32 + g * 4 + j) * 1024 + col]      = acc0[j];
            out[(size_t)(w * 32 + 16 + g * 4 + j) * 1024 + col] = acc1[j];
        }
        cur ^= 1;
    }
#undef FC1_STAGE
}

// ---------------------------------------------------------------------------
// prep: embed lookup + split3 (blocks 0..127) and h0 split3 (blocks 128..383)
__global__ void prep_k(const int* __restrict__ word, const float* __restrict__ emb,
                       const float* __restrict__ h0,
                       short* __restrict__ xh, short* __restrict__ xm, short* __restrict__ xl,
                       short* __restrict__ h0h, short* __restrict__ h0m, short* __restrict__ h0l)
{
    const int blk = blockIdx.x, t = threadIdx.x;
    const float* src; short *dh, *dm, *dl; size_t off;
    if (blk < 128) {
        src = emb + (size_t)word[blk] * H; off = (size_t)blk * H;
        dh = xh; dm = xm; dl = xl;
    } else {
        const int i = blk - 128;
        src = h0 + (size_t)i * H; off = (size_t)i * H;
        dh = h0h; dm = h0m; dl = h0l;
    }
    const float4 v = ((const float4*)src)[t];
    short4v sh, sm, sl;
    S3 s;
    s = split3(v.x); sh.x = s.h; sm.x = s.m; sl.x = s.l;
    s = split3(v.y); sh.y = s.h; sm.y = s.m; sl.y = s.l;
    s = split3(v.z); sh.z = s.h; sm.z = s.m; sl.z = s.l;
    s = split3(v.w); sh.w = s.h; sm.w = s.m; sl.w = s.l;
    *(short4v*)(dh + off + t * 4) = sh;
    *(short4v*)(dm + off + t * 4) = sm;
    *(short4v*)(dl + off + t * 4) = sl;
}

// sum 8 partials + biases -> LSTM cell -> h (fp32), c (fp32), x splits (bf16)
__global__ void lstm_cell_k(const float* __restrict__ part,
                            const float* __restrict__ bih, const float* __restrict__ bhh,
                            const float* __restrict__ c0,
                            float* __restrict__ h_out, float* __restrict__ c_out,
                            short* __restrict__ xh, short* __restrict__ xm,
                            short* __restrict__ xl)
{
    const int idx = blockIdx.x * 256 + threadIdx.x;   // < 128*1024
    const int b = idx >> 10, hh = idx & 1023;
    const size_t base = (size_t)b * 4096;
    float g[4];
    #pragma unroll
    for (int j = 0; j < 4; ++j) {
        const int o = hh + j * H;
        float s = bih[o] + bhh[o];
        #pragma unroll
        for (int i = 0; i < 8; ++i) s += part[base + o + (size_t)i * 524288];
        g[j] = s;
    }
    const float c = sigf(g[1]) * c0[idx] + sigf(g[0]) * tanhf(g[2]);
    const float h = sigf(g[3]) * tanhf(c);
    c_out[idx] = c;
    h_out[idx] = h;
    const S3 s = split3(h);
    xh[idx] = s.h; xm[idx] = s.m; xl[idx] = s.l;
}

// fused: finish p from 16 t1pre partials -> window -> scores -> softmax*gauss
// -> a (out) and ctx (bf16)
__global__ void attn_ctx_k(const float* __restrict__ part, const float* __restrict__ b1,
                           const float* __restrict__ w2v, const float* __restrict__ b2,
                           const int* __restrict__ Sptr,
                           const float* __restrict__ x, const float* __restrict__ enc,
                           float* __restrict__ a_out, short* __restrict__ ctxb)
{
    __shared__ float red[256];
    __shared__ float so[H];
    __shared__ float swred[4][MAXW];
    __shared__ float ssc[MAXW];
    __shared__ float sa[MAXW];
    __shared__ float sp;
    __shared__ int sw0, sw1;
    const int b = blockIdx.x, t = threadIdx.x;
    const int lane = t & 63, wvv = t >> 6;

    {
        const float* pa = part + (size_t)b * 512;
        float v = 0.f;
        #pragma unroll
        for (int jj = 0; jj < 2; ++jj) {
            const int j = t + jj * 256;
            float sgm = b1[j];
            #pragma unroll
            for (int i = 0; i < 16; ++i) sgm += pa[j + (size_t)i * 65536];
            v += tanhf(sgm) * w2v[j];
        }
        red[t] = v;
        __syncthreads();
        for (int s = 128; s > 0; s >>= 1) {
            if (t < s) red[t] += red[t + s];
            __syncthreads();
        }
        if (t == 0) {
            const float S = (float)Sptr[0];
            const float sv = S * sigf(red[0] + b2[0]);
            sp  = sv;
            sw0 = (int)rintf(fmaxf(sv - (float)WSZ, 0.f));
            sw1 = (int)rintf(fminf(sv + (float)WSZ, S - 1.f));
        }
    }
    for (int h = t; h < H; h += 256) so[h] = x[(size_t)b * H + h];
    __syncthreads();
    const int w0 = sw0, w1e = sw1;
    const float pbv = sp;

    float ps[MAXW];
    #pragma unroll
    for (int w = 0; w < MAXW; ++w) ps[w] = 0.f;
    for (int h4 = t; h4 < H / 4; h4 += 256) {
        const float4 o = ((const float4*)so)[h4];
        #pragma unroll
        for (int w = 0; w < MAXW; ++w) {
            const int idx = w0 + w;
            if (idx <= w1e) {
                const float4 e = *(const float4*)(enc + ((size_t)idx * B + b) * H + h4 * 4);
                ps[w] += o.x * e.x + o.y * e.y + o.z * e.z + o.w * e.w;
            }
        }
    }
    #pragma unroll
    for (int w = 0; w < MAXW; ++w) {
        float v = ps[w];
        for (int off = 32; off > 0; off >>= 1) v += __shfl_down(v, off);
        if (lane == 0) swred[wvv][w] = v;
    }
    __syncthreads();
    if (t == 0) {
        float m = -1e30f;
        for (int w = 0; w < MAXW; ++w) {
            const float s = swred[0][w] + swred[1][w] + swred[2][w] + swred[3][w];
            ssc[w] = s;
            m = fmaxf(m, s);
        }
        float den = 0.f;
        for (int w = 0; w < MAXW; ++w) den += expf(ssc[w] - m);
        for (int w = 0; w < MAXW; ++w) {
            const int idx = w0 + w;
            const float gauss = (idx <= w1e) ? expf(((float)idx - pbv) / 50.0f) : 0.f;
            sa[w] = expf(ssc[w] - m) / den * gauss;
        }
    }
    __syncthreads();
    if (t < MAXW) a_out[b * MAXW + t] = sa[t];
    for (int h4 = t; h4 < H / 4; h4 += 256) {
        float4 acc = {0.f, 0.f, 0.f, 0.f};
        #pragma unroll
        for (int w = 0; w < MAXW; ++w) {
            const int idx = w0 + w;
            if (idx <= w1e) {
                const float4 e = *(const float4*)(enc + ((size_t)idx * B + b) * H + h4 * 4);
                acc.x += sa[w] * e.x; acc.y += sa[w] * e.y;
                acc.z += sa[w] * e.z; acc.w += sa[w] * e.w;
            }
        }
        short4v s;
        s.x = (short)rnebf(acc.x); s.y = (short)rnebf(acc.y);
        s.z = (short)rnebf(acc.z); s.w = (short)rnebf(acc.w);
        *(short4v*)(ctxb + (size_t)b * H + h4 * 4) = s;
    }
}

// sum 16 fc1 partials + bias -> tanh -> o2 (fp32, d_out) + o2b (bf16)
__global__ void fc1_fin_k(const float* __restrict__ part, const float* __restrict__ bias,
                          float* __restrict__ o2, short* __restrict__ o2b)
{
    const int idx = blockIdx.x * 256 + threadIdx.x;   // < 128*1024
    const int n = idx & 1023;
    float v = bias[n];
    #pragma unroll
    for (int i = 0; i < 16; ++i) v += part[idx + (size_t)i * 131072];
    v = tanhf(v);
    o2[idx] = v;
    o2b[idx] = (short)rnebf(v);
}

// fused fc2-finish + log_softmax: row = p0 + p1 + bias held in registers.
__global__ __launch_bounds__(1024) void lsm_k(
    const float* __restrict__ p0, const float* __restrict__ p1,
    const float* __restrict__ bias, float* __restrict__ y)
{
    __shared__ float sm[16], ss[16], slse;
    const int b = blockIdx.x, t = threadIdx.x;
    const float* r0 = p0 + (size_t)b * V;
    const float* r1 = p1 + (size_t)b * V;
    float* yrow = y + (size_t)b * V;

    f32x4 r[8];
    float m = -1e30f, s = 0.f;
    #pragma unroll
    for (int i = 0; i < 8; ++i) {
        const int v4 = t + i * 1024;
        if (v4 < V / 4) {
            const f32x4 a = ((const f32x4*)r0)[v4];
            const f32x4 c = ((const f32x4*)r1)[v4];
            const f32x4 bv = ((const f32x4*)bias)[v4];
            f32x4 q;
            q.x = a.x + c.x + bv.x; q.y = a.y + c.y + bv.y;
            q.z = a.z + c.z + bv.z; q.w = a.w + c.w + bv.w;
            r[i] = q;
            const float mm = fmaxf(fmaxf(q.x, q.y), fmaxf(q.z, q.w));
            if (mm > m) { s *= expf(m - mm); m = mm; }
            s += expf(q.x - m) + expf(q.y - m) + expf(q.z - m) + expf(q.w - m);
        }
    }
    for (int off = 32; off > 0; off >>= 1) {
        const float mo = __shfl_down(m, off), so = __shfl_down(s, off);
        const float mn = fmaxf(m, mo);
        s = s * expf(m - mn) + so * expf(mo - mn);
        m = mn;
    }
    const int wv = t >> 6, lane = t & 63;
    if (lane == 0) { sm[wv] = m; ss[wv] = s; }
    __syncthreads();
    if (t == 0) {
        float M = sm[0], S = ss[0];
        for (int i = 1; i < 16; ++i) {
            const float mn = fmaxf(M, sm[i]);
            S = S * expf(M - mn) + ss[i] * expf(sm[i] - mn);
            M = mn;
        }
        slse = M + logf(S);
    }
    __syncthreads();
    const float lse = slse;
    #pragma unroll
    for (int i = 0; i < 8; ++i) {
        const int v4 = t + i * 1024;
        if (v4 < V / 4) {
            f32x4 q = r[i];
            q.x -= lse; q.y -= lse; q.z -= lse; q.w -= lse;
            ((f32x4*)yrow)[v4] = q;
        }
    }
}

} // namespace

extern "C" void kernel_launch(void* const* d_in, const int* in_sizes, int n_in,
                              void* d_out, int out_size, void* d_ws, size_t ws_size,
                              hipStream_t stream)
{
    const int*   Sp   = (const int*)d_in[0];
    const float* enc  = (const float*)d_in[1];
    const int*   word = (const int*)d_in[2];
    const float* h0   = (const float*)d_in[3];
    const float* c0   = (const float*)d_in[4];
    const float* emb  = (const float*)d_in[5];
    const float* Wih  = (const float*)d_in[6];
    const float* Whh  = (const float*)d_in[7];
    const float* bih  = (const float*)d_in[8];
    const float* bhh  = (const float*)d_in[9];
    const float* aw1  = (const float*)d_in[10];
    const float* ab1  = (const float*)d_in[11];
    const float* aw2  = (const float*)d_in[12];
    const float* ab2  = (const float*)d_in[13];
    const float* f1w  = (const float*)d_in[14];
    const float* f1b  = (const float*)d_in[15];
    const float* f2w  = (const float*)d_in[16];
    const float* f2b  = (const float*)d_in[17];

    float* outp = (float*)d_out;
    float* y    = outp;                       // 128*32000
    float* o2   = y  + (size_t)B * V;         // 128*1024
    float* hN   = o2 + (size_t)B * H;         // 2*128*1024
    float* cN   = hN + 2 * (size_t)B * H;     // 2*128*1024
    float* aO   = cN + 2 * (size_t)B * H;     // 128*21

    char* wsp = (char*)d_ws;
    short* xh   = (short*)wsp;  wsp += (size_t)B * H * 2;
    short* xm   = (short*)wsp;  wsp += (size_t)B * H * 2;
    short* xl   = (short*)wsp;  wsp += (size_t)B * H * 2;
    short* h0h  = (short*)wsp;  wsp += (size_t)2 * B * H * 2;
    short* h0m  = (short*)wsp;  wsp += (size_t)2 * B * H * 2;
    short* h0l  = (short*)wsp;  wsp += (size_t)2 * B * H * 2;
    short* ctxb = (short*)wsp;  wsp += (size_t)B * H * 2;
    short* o2b  = (short*)wsp;  wsp += (size_t)B * H * 2;
    float* part = (float*)wsp;  wsp += (size_t)16 * B * 4 * H * 4;  // 32 MB
    float* pf2  = (float*)wsp;  wsp += (size_t)2 * B * V * 4;       // 32.8 MB

    prep_k<<<dim3(384), dim3(256), 0, stream>>>(word, emb, h0, xh, xm, xl, h0h, h0m, h0l);

    for (int l = 0; l < 2; ++l) {
        lstm_gemm<<<dim3(64, 8), dim3(256), 0, stream>>>(
            xh, xm, xl,
            h0h + (size_t)l * B * H, h0m + (size_t)l * B * H, h0l + (size_t)l * B * H,
            Wih + (size_t)l * 4 * H * H, Whh + (size_t)l * 4 * H * H,
            part);
        lstm_cell_k<<<dim3(B * H / 256), dim3(256), 0, stream>>>(
            part, bih + (size_t)l * 4 * H, bhh + (size_t)l * 4 * H,
            c0 + (size_t)l * B * H,
            hN + (size_t)l * B * H, cN + (size_t)l * B * H, xh, xm, xl);
    }

    const float* hfin = hN + (size_t)B * H;  // last layer h (fp32)

    // attn position pre-GEMM: t1pre = h @ w1^T (split3 MFMA, 16 K-partials)
    gemm_x3<<<dim3(8, 16), dim3(256), 0, stream>>>(
        xh, xm, xl, xh, xm, xl, aw1, aw1, 512, 64, 4, part);
    attn_ctx_k<<<dim3(B), dim3(256), 0, stream>>>(
        part, ab1, aw2, ab2, Sp, hfin, enc, aO, ctxb);

    // fc1: [ctx | out] @ f1w^T -> 16 sequential-staged split-K partials -> tanh
    fc1_gemm<<<dim3(16, 16), dim3(256), 0, stream>>>(ctxb, xh, f1w, part);
    fc1_fin_k<<<dim3(B * H / 256), dim3(256), 0, stream>>>(part, f1b, o2, o2b);

    // fc2 (round-13 split-K): row-sequential staged W -> 2 K-partials
    fc2_gemm<<<dim3(V / 64, 2), dim3(256), 0, stream>>>(o2b, f2w, pf2);

    // fused fc2-finish (+bias) and log_softmax
    lsm_k<<<dim3(B), dim3(1024), 0, stream>>>(pf2, pf2 + (size_t)B * V, f2b, y);
}

// Round 18
// 164.820 us; speedup vs baseline: 1.0441x; 1.0205x over previous
//
#include <hip/hip_runtime.h>
#include <math.h>

namespace {

constexpr int B    = 128;
constexpr int H    = 1024;
constexpr int V    = 32000;
constexpr int WSZ  = 10;
constexpr int MAXW = 2 * WSZ + 1;   // 21

typedef __attribute__((ext_vector_type(8))) short bf16x8;
typedef __attribute__((ext_vector_type(4))) short short4v;
typedef __attribute__((ext_vector_type(4))) float f32x4;

__device__ __forceinline__ float sigf(float x) { return 1.0f / (1.0f + expf(-x)); }

__device__ __forceinline__ unsigned short rnebf(float f) {
    unsigned u = __float_as_uint(f);
    u += 0x7fffu + ((u >> 16) & 1u);
    return (unsigned short)(u >> 16);
}

__device__ __forceinline__ float bf2f(short s) {
    return __uint_as_float(((unsigned)(unsigned short)s) << 16);
}

__device__ __forceinline__ bf16x8 cvt8(const f32x4 a, const f32x4 b) {
    bf16x8 r;
    r[0] = (short)rnebf(a.x); r[1] = (short)rnebf(a.y);
    r[2] = (short)rnebf(a.z); r[3] = (short)rnebf(a.w);
    r[4] = (short)rnebf(b.x); r[5] = (short)rnebf(b.y);
    r[6] = (short)rnebf(b.z); r[7] = (short)rnebf(b.w);
    return r;
}

// async 16B global -> LDS (gfx950 global_load_lds dwordx4)
// dest must be wave-uniform base; HW adds lane*16.
__device__ __forceinline__ void gl_lds16(const float* g, float* l) {
    __builtin_amdgcn_global_load_lds(
        (const __attribute__((address_space(1))) unsigned int*)g,
        (__attribute__((address_space(3))) unsigned int*)l,
        16, 0, 0);
}

struct S3 { short h, m, l; };

// exact 3-way truncation split: x == h + m + l + delta, |delta| <~ 2^-24 |x|
__device__ __forceinline__ S3 split3(float x) {
    S3 r;
    const unsigned uh = __float_as_uint(x) & 0xFFFF0000u;
    const float fh = __uint_as_float(uh);
    const float r1 = x - fh;
    const unsigned um = __float_as_uint(r1) & 0xFFFF0000u;
    const float fm = __uint_as_float(um);
    const float r2 = r1 - fm;
    const unsigned ul = __float_as_uint(r2) & 0xFFFF0000u;
    r.h = (short)(uh >> 16);
    r.m = (short)(um >> 16);
    r.l = (short)(ul >> 16);
    return r;
}

__device__ __forceinline__ void split8(const f32x4 a, const f32x4 b,
                                       bf16x8& wh, bf16x8& wm, bf16x8& wl) {
    S3 s;
    s = split3(a.x); wh[0] = s.h; wm[0] = s.m; wl[0] = s.l;
    s = split3(a.y); wh[1] = s.h; wm[1] = s.m; wl[1] = s.l;
    s = split3(a.z); wh[2] = s.h; wm[2] = s.m; wl[2] = s.l;
    s = split3(a.w); wh[3] = s.h; wm[3] = s.m; wl[3] = s.l;
    s = split3(b.x); wh[4] = s.h; wm[4] = s.m; wl[4] = s.l;
    s = split3(b.y); wh[5] = s.h; wm[5] = s.m; wl[5] = s.l;
    s = split3(b.z); wh[6] = s.h; wm[6] = s.m; wl[6] = s.l;
    s = split3(b.w); wh[7] = s.h; wm[7] = s.m; wl[7] = s.l;
}

// ---------------------------------------------------------------------------
// LSTM split3 GEMM, row-sequential staged W (proven).
// ---------------------------------------------------------------------------
__global__ __launch_bounds__(256, 2) void lstm_gemm(
    const short* __restrict__ Ah0, const short* __restrict__ Am0, const short* __restrict__ Al0,
    const short* __restrict__ Ah1, const short* __restrict__ Am1, const short* __restrict__ Al1,
    const float* __restrict__ W0, const float* __restrict__ W1,
    float* __restrict__ outbase)
{
    __shared__ float wt[2][4160];   // 2 x (16 rows x 260 f32)

    const int t    = threadIdx.x;
    const int lane = t & 63;
    const int w    = t >> 6;
    const int m16  = lane & 15;
    const int g    = lane >> 4;
    const int n0   = blockIdx.x * 64;
    const int y    = blockIdx.y;
    const int src  = y >> 2;
    const int k0   = (y & 3) * 256;
    const short* Ah = src ? Ah1 : Ah0;
    const short* Am = src ? Am1 : Am0;
    const short* Al = src ? Al1 : Al0;
    const float* W  = src ? W1  : W0;
    float* out = outbase + (size_t)y * 128 * 4096;

    bf16x8 ah[2][8], am[2][8], al[2][8];
    #pragma unroll
    for (int q = 0; q < 2; ++q) {
        const size_t ao = (size_t)((w * 2 + q) * 16 + m16) * 1024 + k0 + g * 8;
        #pragma unroll
        for (int s = 0; s < 8; ++s) {
            ah[q][s] = *(const bf16x8*)(Ah + ao + s * 32);
            am[q][s] = *(const bf16x8*)(Am + ao + s * 32);
            al[q][s] = *(const bf16x8*)(Al + ao + s * 32);
        }
    }

#define LSTM_STAGE(BUF, C)                                                  \
    {                                                                       \
        _Pragma("unroll")                                                   \
        for (int i = 0; i < 5; ++i) {                                       \
            const int idx = i * 256 + t;                                    \
            const int rr  = idx / 65;                                       \
            const int pp  = idx - rr * 65;                                  \
            if (idx < 1040 && pp < 64) {                                    \
                const float* s_ = W + (size_t)(n0 + (C) * 16 + rr) * 1024   \
                                + k0 + pp * 4;                              \
                gl_lds16(s_, &wt[BUF][(size_t)(i * 256 + w * 64) * 4]);     \
            }                                                               \
        }                                                                   \
    }

    LSTM_STAGE(0, 0)
    int cur = 0;
    #pragma unroll
    for (int c = 0; c < 4; ++c) {
        __syncthreads();
        if (c < 3) {
            if (cur == 0) LSTM_STAGE(1, c + 1)
            else          LSTM_STAGE(0, c + 1)
        }
        f32x4 acc0 = {}, acc1 = {};
        const float* lrow = &wt[cur][m16 * 260 + g * 8];
        #pragma unroll
        for (int s = 0; s < 8; ++s) {
            const f32x4 wa = *(const f32x4*)(lrow + s * 32);
            const f32x4 wb = *(const f32x4*)(lrow + s * 32 + 4);
            bf16x8 wh, wm, wl;
            split8(wa, wb, wh, wm, wl);
            acc0 = __builtin_amdgcn_mfma_f32_16x16x32_bf16(ah[0][s], wh, acc0, 0, 0, 0);
            acc0 = __builtin_amdgcn_mfma_f32_16x16x32_bf16(ah[0][s], wm, acc0, 0, 0, 0);
            acc0 = __builtin_amdgcn_mfma_f32_16x16x32_bf16(am[0][s], wh, acc0, 0, 0, 0);
            acc0 = __builtin_amdgcn_mfma_f32_16x16x32_bf16(ah[0][s], wl, acc0, 0, 0, 0);
            acc0 = __builtin_amdgcn_mfma_f32_16x16x32_bf16(am[0][s], wm, acc0, 0, 0, 0);
            acc0 = __builtin_amdgcn_mfma_f32_16x16x32_bf16(al[0][s], wh, acc0, 0, 0, 0);
            acc1 = __builtin_amdgcn_mfma_f32_16x16x32_bf16(ah[1][s], wh, acc1, 0, 0, 0);
            acc1 = __builtin_amdgcn_mfma_f32_16x16x32_bf16(ah[1][s], wm, acc1, 0, 0, 0);
            acc1 = __builtin_amdgcn_mfma_f32_16x16x32_bf16(am[1][s], wh, acc1, 0, 0, 0);
            acc1 = __builtin_amdgcn_mfma_f32_16x16x32_bf16(ah[1][s], wl, acc1, 0, 0, 0);
            acc1 = __builtin_amdgcn_mfma_f32_16x16x32_bf16(am[1][s], wm, acc1, 0, 0, 0);
            acc1 = __builtin_amdgcn_mfma_f32_16x16x32_bf16(al[1][s], wh, acc1, 0, 0, 0);
        }
        const int col = n0 + c * 16 + m16;
        #pragma unroll
        for (int j = 0; j < 4; ++j) {
            out[(size_t)(w * 32 + g * 4 + j) * 4096 + col]      = acc0[j];
            out[(size_t)(w * 32 + 16 + g * 4 + j) * 4096 + col] = acc1[j];
        }
        cur ^= 1;
    }
#undef LSTM_STAGE
}

// ---------------------------------------------------------------------------
// fc2: split-K, row-sequential staged W, bf16 partials (halved round trip).
// part[y][128 x 32000] (bf16) = A(bf16 128x[k0:+512]) @ W[:, k0:+512]^T
// ---------------------------------------------------------------------------
__global__ __launch_bounds__(256) void fc2_gemm(
    const short* __restrict__ A, const float* __restrict__ W,
    short* __restrict__ outbase)
{
    __shared__ float wt[2][16 * 516];   // 2 x 33024 B

    const int t    = threadIdx.x;
    const int lane = t & 63;
    const int w    = t >> 6;
    const int m16  = lane & 15;
    const int g    = lane >> 4;
    const int n0   = blockIdx.x * 64;
    const int y    = blockIdx.y;
    const int k0   = y * 512;
    short* out = outbase + (size_t)y * B * V;

    bf16x8 a[2][16];
    #pragma unroll
    for (int q = 0; q < 2; ++q) {
        const short* ap = A + (size_t)((w * 2 + q) * 16 + m16) * 1024 + k0 + g * 8;
        #pragma unroll
        for (int s = 0; s < 16; ++s)
            a[q][s] = *(const bf16x8*)(ap + s * 32);
    }

#define FC2_STAGE(BUF, C)                                                   \
    {                                                                       \
        _Pragma("unroll")                                                   \
        for (int i = 0; i < 9; ++i) {                                       \
            const int idx = i * 256 + t;                                    \
            const int rr  = idx / 129;                                      \
            const int pp  = idx - rr * 129;                                 \
            if (idx < 2064 && pp < 128) {                                   \
                const float* src = W + (size_t)(n0 + (C) * 16 + rr) * 1024  \
                                 + k0 + pp * 4;                             \
                gl_lds16(src, &wt[BUF][(size_t)(i * 256 + w * 64) * 4]);    \
            }                                                               \
        }                                                                   \
    }

    FC2_STAGE(0, 0)
    int cur = 0;
    #pragma unroll
    for (int c = 0; c < 4; ++c) {
        __syncthreads();
        if (c < 3) {
            if (cur == 0) FC2_STAGE(1, c + 1)
            else          FC2_STAGE(0, c + 1)
        }
        f32x4 acc0 = {}, acc1 = {};
        const float* lrow = &wt[cur][m16 * 516 + g * 8];
        #pragma unroll
        for (int s = 0; s < 16; ++s) {
            const f32x4 wa = *(const f32x4*)(lrow + s * 32);
            const f32x4 wb = *(const f32x4*)(lrow + s * 32 + 4);
            const bf16x8 bfr = cvt8(wa, wb);
            acc0 = __builtin_amdgcn_mfma_f32_16x16x32_bf16(a[0][s], bfr, acc0, 0, 0, 0);
            acc1 = __builtin_amdgcn_mfma_f32_16x16x32_bf16(a[1][s], bfr, acc1, 0, 0, 0);
        }
        const int col = n0 + c * 16 + m16;
        #pragma unroll
        for (int j = 0; j < 4; ++j) {
            out[(size_t)(w * 32 + g * 4 + j) * V + col]      = (short)rnebf(acc0[j]);
            out[(size_t)(w * 32 + 16 + g * 4 + j) * V + col] = (short)rnebf(acc1[j]);
        }
        cur ^= 1;
    }
#undef FC2_STAGE
}

// ---------------------------------------------------------------------------
// Split-bf16 MFMA GEMM (register W prefetch) — kept for the small attn t1pre.
// ---------------------------------------------------------------------------
__global__ __launch_bounds__(256, 2) void gemm_x3(
    const short* __restrict__ Ah0, const short* __restrict__ Am0, const short* __restrict__ Al0,
    const short* __restrict__ Ah1, const short* __restrict__ Am1, const short* __restrict__ Al1,
    const float* __restrict__ W0, const float* __restrict__ W1,
    int N, int Ksz, int ks_log2, float* __restrict__ outbase)
{
    const int y = blockIdx.y;
    const int src = y >> ks_log2;
    const short* Ah = src ? Ah1 : Ah0;
    const short* Am = src ? Am1 : Am0;
    const short* Al = src ? Al1 : Al0;
    const float* W  = src ? W1  : W0;
    const int k0 = (y & ((1 << ks_log2) - 1)) * Ksz;
    float* out = outbase + (size_t)y * 128 * N;

    const int t    = threadIdx.x;
    const int lane = t & 63;
    const int wv   = t >> 6;
    const int n0   = blockIdx.x * 64 + wv * 16;
    const int m16  = lane & 15;
    const int ko8  = (lane >> 4) * 8;

    const float* wp = W + (size_t)(n0 + m16) * 1024 + k0 + ko8;
    const size_t a0 = (size_t)m16 * 1024 + k0 + ko8;

    f32x4 acc[8] = {};

    f32x4 cwa = *(const f32x4*)(wp);      f32x4 cwb = *(const f32x4*)(wp + 4);
    f32x4 nwa = *(const f32x4*)(wp + 32); f32x4 nwb = *(const f32x4*)(wp + 36);

    for (int kc = 0; kc + 64 < Ksz; kc += 32) {
        bf16x8 ah[8], am[8], al[8];
        #pragma unroll
        for (int m = 0; m < 8; ++m) {
            const size_t ao = a0 + (size_t)m * 16384 + kc;
            ah[m] = *(const bf16x8*)(Ah + ao);
            am[m] = *(const bf16x8*)(Am + ao);
            al[m] = *(const bf16x8*)(Al + ao);
        }
        __builtin_amdgcn_sched_barrier(0);
        const f32x4 fwa = *(const f32x4*)(wp + kc + 64);
        const f32x4 fwb = *(const f32x4*)(wp + kc + 68);
        bf16x8 wh, wm, wl;
        split8(cwa, cwb, wh, wm, wl);
        #pragma unroll
        for (int m = 0; m < 8; ++m) {
            acc[m] = __builtin_amdgcn_mfma_f32_16x16x32_bf16(ah[m], wh, acc[m], 0, 0, 0);
            acc[m] = __builtin_amdgcn_mfma_f32_16x16x32_bf16(ah[m], wm, acc[m], 0, 0, 0);
            acc[m] = __builtin_amdgcn_mfma_f32_16x16x32_bf16(am[m], wh, acc[m], 0, 0, 0);
            acc[m] = __builtin_amdgcn_mfma_f32_16x16x32_bf16(ah[m], wl, acc[m], 0, 0, 0);
            acc[m] = __builtin_amdgcn_mfma_f32_16x16x32_bf16(am[m], wm, acc[m], 0, 0, 0);
            acc[m] = __builtin_amdgcn_mfma_f32_16x16x32_bf16(al[m], wh, acc[m], 0, 0, 0);
        }
        cwa = nwa; cwb = nwb; nwa = fwa; nwb = fwb;
    }
    #pragma unroll
    for (int tail = 0; tail < 2; ++tail) {
        const int kc = Ksz - 64 + tail * 32;
        bf16x8 ah[8], am[8], al[8];
        #pragma unroll
        for (int m = 0; m < 8; ++m) {
            const size_t ao = a0 + (size_t)m * 16384 + kc;
            ah[m] = *(const bf16x8*)(Ah + ao);
            am[m] = *(const bf16x8*)(Am + ao);
            al[m] = *(const bf16x8*)(Al + ao);
        }
        const f32x4 wa = tail ? nwa : cwa;
        const f32x4 wb = tail ? nwb : cwb;
        bf16x8 wh, wm, wl;
        split8(wa, wb, wh, wm, wl);
        #pragma unroll
        for (int m = 0; m < 8; ++m) {
            acc[m] = __builtin_amdgcn_mfma_f32_16x16x32_bf16(ah[m], wh, acc[m], 0, 0, 0);
            acc[m] = __builtin_amdgcn_mfma_f32_16x16x32_bf16(ah[m], wm, acc[m], 0, 0, 0);
            acc[m] = __builtin_amdgcn_mfma_f32_16x16x32_bf16(am[m], wh, acc[m], 0, 0, 0);
            acc[m] = __builtin_amdgcn_mfma_f32_16x16x32_bf16(ah[m], wl, acc[m], 0, 0, 0);
            acc[m] = __builtin_amdgcn_mfma_f32_16x16x32_bf16(am[m], wm, acc[m], 0, 0, 0);
            acc[m] = __builtin_amdgcn_mfma_f32_16x16x32_bf16(al[m], wh, acc[m], 0, 0, 0);
        }
    }

    #pragma unroll
    for (int m = 0; m < 8; ++m) {
        const int rbase = m * 16 + (lane >> 4) * 4;
        #pragma unroll
        for (int r = 0; r < 4; ++r)
            out[(size_t)(rbase + r) * N + n0 + m16] = acc[m][r];
    }
}

// ---------------------------------------------------------------------------
// fc1 v2: row-sequential staged W (proven).
// ---------------------------------------------------------------------------
__global__ __launch_bounds__(256, 2) void fc1_gemm(
    const short* __restrict__ A0, const short* __restrict__ A1,
    const float* __restrict__ W, float* __restrict__ outbase)
{
    __shared__ float wt[2][16 * 132];   // 2 x 8448 B

    const int t    = threadIdx.x;
    const int lane = t & 63;
    const int w    = t >> 6;
    const int m16  = lane & 15;
    const int g    = lane >> 4;
    const int n0   = blockIdx.x * 64;
    const int y    = blockIdx.y;
    const int src  = y >> 3;
    const int k0   = (y & 7) * 128;
    const int wk0  = src * 1024 + k0;
    const short* A = src ? A1 : A0;
    float* out = outbase + (size_t)y * 128 * 1024;

    bf16x8 a[2][4];
    #pragma unroll
    for (int q = 0; q < 2; ++q) {
        const short* ap = A + (size_t)((w * 2 + q) * 16 + m16) * 1024 + k0 + g * 8;
        #pragma unroll
        for (int s = 0; s < 4; ++s)
            a[q][s] = *(const bf16x8*)(ap + s * 32);
    }

#define FC1_STAGE(BUF, C)                                                   \
    {                                                                       \
        _Pragma("unroll")                                                   \
        for (int i = 0; i < 3; ++i) {                                       \
            const int idx = i * 256 + t;                                    \
            const int rr  = idx / 33;                                       \
            const int pp  = idx - rr * 33;                                  \
            if (idx < 528 && pp < 32) {                                     \
                const float* s_ = W + (size_t)(n0 + (C) * 16 + rr) * 2048   \
                                + wk0 + pp * 4;                             \
                gl_lds16(s_, &wt[BUF][(size_t)(i * 256 + w * 64) * 4]);     \
            }                                                               \
        }                                                                   \
    }

    FC1_STAGE(0, 0)
    int cur = 0;
    #pragma unroll
    for (int c = 0; c < 4; ++c) {
        __syncthreads();
        if (c < 3) {
            if (cur == 0) FC1_STAGE(1, c + 1)
            else          FC1_STAGE(0, c + 1)
        }
        f32x4 acc0 = {}, acc1 = {};
        const float* lrow = &wt[cur][m16 * 132 + g * 8];
        #pragma unroll
        for (int s = 0; s < 4; ++s) {
            const f32x4 wa = *(const f32x4*)(lrow + s * 32);
            const f32x4 wb = *(const f32x4*)(lrow + s * 32 + 4);
            const bf16x8 bfr = cvt8(wa, wb);
            acc0 = __builtin_amdgcn_mfma_f32_16x16x32_bf16(a[0][s], bfr, acc0, 0, 0, 0);
            acc1 = __builtin_amdgcn_mfma_f32_16x16x32_bf16(a[1][s], bfr, acc1, 0, 0, 0);
        }
        const int col = n0 + c * 16 + m16;
        #pragma unroll
        for (int j = 0; j < 4; ++j) {
            out[(size_t)(w * 32 + g * 4 + j) * 1024 + col]      = acc0[j];
            out[(size_t)(w * 32 + 16 + g * 4 + j) * 1024 + col] = acc1[j];
        }
        cur ^= 1;
    }
#undef FC1_STAGE
}

// ---------------------------------------------------------------------------
// prep: embed lookup + split3 (blocks 0..127) and h0 split3 (blocks 128..383)
__global__ void prep_k(const int* __restrict__ word, const float* __restrict__ emb,
                       const float* __restrict__ h0,
                       short* __restrict__ xh, short* __restrict__ xm, short* __restrict__ xl,
                       short* __restrict__ h0h, short* __restrict__ h0m, short* __restrict__ h0l)
{
    const int blk = blockIdx.x, t = threadIdx.x;
    const float* src; short *dh, *dm, *dl; size_t off;
    if (blk < 128) {
        src = emb + (size_t)word[blk] * H; off = (size_t)blk * H;
        dh = xh; dm = xm; dl = xl;
    } else {
        const int i = blk - 128;
        src = h0 + (size_t)i * H; off = (size_t)i * H;
        dh = h0h; dm = h0m; dl = h0l;
    }
    const float4 v = ((const float4*)src)[t];
    short4v sh, sm, sl;
    S3 s;
    s = split3(v.x); sh.x = s.h; sm.x = s.m; sl.x = s.l;
    s = split3(v.y); sh.y = s.h; sm.y = s.m; sl.y = s.l;
    s = split3(v.z); sh.z = s.h; sm.z = s.m; sl.z = s.l;
    s = split3(v.w); sh.w = s.h; sm.w = s.m; sl.w = s.l;
    *(short4v*)(dh + off + t * 4) = sh;
    *(short4v*)(dm + off + t * 4) = sm;
    *(short4v*)(dl + off + t * 4) = sl;
}

// sum 8 partials + biases -> LSTM cell -> h (fp32), c (fp32), x splits (bf16)
__global__ void lstm_cell_k(const float* __restrict__ part,
                            const float* __restrict__ bih, const float* __restrict__ bhh,
                            const float* __restrict__ c0,
                            float* __restrict__ h_out, float* __restrict__ c_out,
                            short* __restrict__ xh, short* __restrict__ xm,
                            short* __restrict__ xl)
{
    const int idx = blockIdx.x * 256 + threadIdx.x;   // < 128*1024
    const int b = idx >> 10, hh = idx & 1023;
    const size_t base = (size_t)b * 4096;
    float g[4];
    #pragma unroll
    for (int j = 0; j < 4; ++j) {
        const int o = hh + j * H;
        float s = bih[o] + bhh[o];
        #pragma unroll
        for (int i = 0; i < 8; ++i) s += part[base + o + (size_t)i * 524288];
        g[j] = s;
    }
    const float c = sigf(g[1]) * c0[idx] + sigf(g[0]) * tanhf(g[2]);
    const float h = sigf(g[3]) * tanhf(c);
    c_out[idx] = c;
    h_out[idx] = h;
    const S3 s = split3(h);
    xh[idx] = s.h; xm[idx] = s.m; xl[idx] = s.l;
}

// fused: finish p from 16 t1pre partials -> window -> scores -> softmax*gauss
// -> a (out) and ctx (bf16)
__global__ void attn_ctx_k(const float* __restrict__ part, const float* __restrict__ b1,
                           const float* __restrict__ w2v, const float* __restrict__ b2,
                           const int* __restrict__ Sptr,
                           const float* __restrict__ x, const float* __restrict__ enc,
                           float* __restrict__ a_out, short* __restrict__ ctxb)
{
    __shared__ float red[256];
    __shared__ float so[H];
    __shared__ float swred[4][MAXW];
    __shared__ float ssc[MAXW];
    __shared__ float sa[MAXW];
    __shared__ float sp;
    __shared__ int sw0, sw1;
    const int b = blockIdx.x, t = threadIdx.x;
    const int lane = t & 63, wvv = t >> 6;

    {
        const float* pa = part + (size_t)b * 512;
        float v = 0.f;
        #pragma unroll
        for (int jj = 0; jj < 2; ++jj) {
            const int j = t + jj * 256;
            float sgm = b1[j];
            #pragma unroll
            for (int i = 0; i < 16; ++i) sgm += pa[j + (size_t)i * 65536];
            v += tanhf(sgm) * w2v[j];
        }
        red[t] = v;
        __syncthreads();
        for (int s = 128; s > 0; s >>= 1) {
            if (t < s) red[t] += red[t + s];
            __syncthreads();
        }
        if (t == 0) {
            const float S = (float)Sptr[0];
            const float sv = S * sigf(red[0] + b2[0]);
            sp  = sv;
            sw0 = (int)rintf(fmaxf(sv - (float)WSZ, 0.f));
            sw1 = (int)rintf(fminf(sv + (float)WSZ, S - 1.f));
        }
    }
    for (int h = t; h < H; h += 256) so[h] = x[(size_t)b * H + h];
    __syncthreads();
    const int w0 = sw0, w1e = sw1;
    const float pbv = sp;

    float ps[MAXW];
    #pragma unroll
    for (int w = 0; w < MAXW; ++w) ps[w] = 0.f;
    for (int h4 = t; h4 < H / 4; h4 += 256) {
        const float4 o = ((const float4*)so)[h4];
        #pragma unroll
        for (int w = 0; w < MAXW; ++w) {
            const int idx = w0 + w;
            if (idx <= w1e) {
                const float4 e = *(const float4*)(enc + ((size_t)idx * B + b) * H + h4 * 4);
                ps[w] += o.x * e.x + o.y * e.y + o.z * e.z + o.w * e.w;
            }
        }
    }
    #pragma unroll
    for (int w = 0; w < MAXW; ++w) {
        float v = ps[w];
        for (int off = 32; off > 0; off >>= 1) v += __shfl_down(v, off);
        if (lane == 0) swred[wvv][w] = v;
    }
    __syncthreads();
    if (t == 0) {
        float m = -1e30f;
        for (int w = 0; w < MAXW; ++w) {
            const float s = swred[0][w] + swred[1][w] + swred[2][w] + swred[3][w];
            ssc[w] = s;
            m = fmaxf(m, s);
        }
        float den = 0.f;
        for (int w = 0; w < MAXW; ++w) den += expf(ssc[w] - m);
        for (int w = 0; w < MAXW; ++w) {
            const int idx = w0 + w;
            const float gauss = (idx <= w1e) ? expf(((float)idx - pbv) / 50.0f) : 0.f;
            sa[w] = expf(ssc[w] - m) / den * gauss;
        }
    }
    __syncthreads();
    if (t < MAXW) a_out[b * MAXW + t] = sa[t];
    for (int h4 = t; h4 < H / 4; h4 += 256) {
        float4 acc = {0.f, 0.f, 0.f, 0.f};
        #pragma unroll
        for (int w = 0; w < MAXW; ++w) {
            const int idx = w0 + w;
            if (idx <= w1e) {
                const float4 e = *(const float4*)(enc + ((size_t)idx * B + b) * H + h4 * 4);
                acc.x += sa[w] * e.x; acc.y += sa[w] * e.y;
                acc.z += sa[w] * e.z; acc.w += sa[w] * e.w;
            }
        }
        short4v s;
        s.x = (short)rnebf(acc.x); s.y = (short)rnebf(acc.y);
        s.z = (short)rnebf(acc.z); s.w = (short)rnebf(acc.w);
        *(short4v*)(ctxb + (size_t)b * H + h4 * 4) = s;
    }
}

// sum 16 fc1 partials + bias -> tanh -> o2 (fp32, d_out) + o2b (bf16)
__global__ void fc1_fin_k(const float* __restrict__ part, const float* __restrict__ bias,
                          float* __restrict__ o2, short* __restrict__ o2b)
{
    const int idx = blockIdx.x * 256 + threadIdx.x;   // < 128*1024
    const int n = idx & 1023;
    float v = bias[n];
    #pragma unroll
    for (int i = 0; i < 16; ++i) v += part[idx + (size_t)i * 131072];
    v = tanhf(v);
    o2[idx] = v;
    o2b[idx] = (short)rnebf(v);
}

// fused fc2-finish + log_softmax: row = bf16(p0) + bf16(p1) + bias in registers.
__global__ __launch_bounds__(1024) void lsm_k(
    const short* __restrict__ p0, const short* __restrict__ p1,
    const float* __restrict__ bias, float* __restrict__ y)
{
    __shared__ float sm[16], ss[16], slse;
    const int b = blockIdx.x, t = threadIdx.x;
    const short* r0 = p0 + (size_t)b * V;
    const short* r1 = p1 + (size_t)b * V;
    float* yrow = y + (size_t)b * V;

    f32x4 r[8];
    float m = -1e30f, s = 0.f;
    #pragma unroll
    for (int i = 0; i < 8; ++i) {
        const int v4 = t + i * 1024;
        if (v4 < V / 4) {
            const short4v a = ((const short4v*)r0)[v4];
            const short4v c = ((const short4v*)r1)[v4];
            const f32x4 bv = ((const f32x4*)bias)[v4];
            f32x4 q;
            q.x = bf2f(a.x) + bf2f(c.x) + bv.x;
            q.y = bf2f(a.y) + bf2f(c.y) + bv.y;
            q.z = bf2f(a.z) + bf2f(c.z) + bv.z;
            q.w = bf2f(a.w) + bf2f(c.w) + bv.w;
            r[i] = q;
            const float mm = fmaxf(fmaxf(q.x, q.y), fmaxf(q.z, q.w));
            if (mm > m) { s *= expf(m - mm); m = mm; }
            s += expf(q.x - m) + expf(q.y - m) + expf(q.z - m) + expf(q.w - m);
        }
    }
    for (int off = 32; off > 0; off >>= 1) {
        const float mo = __shfl_down(m, off), so = __shfl_down(s, off);
        const float mn = fmaxf(m, mo);
        s = s * expf(m - mn) + so * expf(mo - mn);
        m = mn;
    }
    const int wv = t >> 6, lane = t & 63;
    if (lane == 0) { sm[wv] = m; ss[wv] = s; }
    __syncthreads();
    if (t == 0) {
        float M = sm[0], S = ss[0];
        for (int i = 1; i < 16; ++i) {
            const float mn = fmaxf(M, sm[i]);
            S = S * expf(M - mn) + ss[i] * expf(sm[i] - mn);
            M = mn;
        }
        slse = M + logf(S);
    }
    __syncthreads();
    const float lse = slse;
    #pragma unroll
    for (int i = 0; i < 8; ++i) {
        const int v4 = t + i * 1024;
        if (v4 < V / 4) {
            f32x4 q = r[i];
            q.x -= lse; q.y -= lse; q.z -= lse; q.w -= lse;
            ((f32x4*)yrow)[v4] = q;
        }
    }
}

} // namespace

extern "C" void kernel_launch(void* const* d_in, const int* in_sizes, int n_in,
                              void* d_out, int out_size, void* d_ws, size_t ws_size,
                              hipStream_t stream)
{
    const int*   Sp   = (const int*)d_in[0];
    const float* enc  = (const float*)d_in[1];
    const int*   word = (const int*)d_in[2];
    const float* h0   = (const float*)d_in[3];
    const float* c0   = (const float*)d_in[4];
    const float* emb  = (const float*)d_in[5];
    const float* Wih  = (const float*)d_in[6];
    const float* Whh  = (const float*)d_in[7];
    const float* bih  = (const float*)d_in[8];
    const float* bhh  = (const float*)d_in[9];
    const float* aw1  = (const float*)d_in[10];
    const float* ab1  = (const float*)d_in[11];
    const float* aw2  = (const float*)d_in[12];
    const float* ab2  = (const float*)d_in[13];
    const float* f1w  = (const float*)d_in[14];
    const float* f1b  = (const float*)d_in[15];
    const float* f2w  = (const float*)d_in[16];
    const float* f2b  = (const float*)d_in[17];

    float* outp = (float*)d_out;
    float* y    = outp;                       // 128*32000
    float* o2   = y  + (size_t)B * V;         // 128*1024
    float* hN   = o2 + (size_t)B * H;         // 2*128*1024
    float* cN   = hN + 2 * (size_t)B * H;     // 2*128*1024
    float* aO   = cN + 2 * (size_t)B * H;     // 128*21

    char* wsp = (char*)d_ws;
    short* xh   = (short*)wsp;  wsp += (size_t)B * H * 2;
    short* xm   = (short*)wsp;  wsp += (size_t)B * H * 2;
    short* xl   = (short*)wsp;  wsp += (size_t)B * H * 2;
    short* h0h  = (short*)wsp;  wsp += (size_t)2 * B * H * 2;
    short* h0m  = (short*)wsp;  wsp += (size_t)2 * B * H * 2;
    short* h0l  = (short*)wsp;  wsp += (size_t)2 * B * H * 2;
    short* ctxb = (short*)wsp;  wsp += (size_t)B * H * 2;
    short* o2b  = (short*)wsp;  wsp += (size_t)B * H * 2;
    float* part = (float*)wsp;  wsp += (size_t)16 * B * 4 * H * 4;  // 32 MB
    short* pf2  = (short*)wsp;  wsp += (size_t)2 * B * V * 2;       // 16.4 MB

    prep_k<<<dim3(384), dim3(256), 0, stream>>>(word, emb, h0, xh, xm, xl, h0h, h0m, h0l);

    for (int l = 0; l < 2; ++l) {
        lstm_gemm<<<dim3(64, 8), dim3(256), 0, stream>>>(
            xh, xm, xl,
            h0h + (size_t)l * B * H, h0m + (size_t)l * B * H, h0l + (size_t)l * B * H,
            Wih + (size_t)l * 4 * H * H, Whh + (size_t)l * 4 * H * H,
            part);
        lstm_cell_k<<<dim3(B * H / 256), dim3(256), 0, stream>>>(
            part, bih + (size_t)l * 4 * H, bhh + (size_t)l * 4 * H,
            c0 + (size_t)l * B * H,
            hN + (size_t)l * B * H, cN + (size_t)l * B * H, xh, xm, xl);
    }

    const float* hfin = hN + (size_t)B * H;  // last layer h (fp32)

    // attn position pre-GEMM: t1pre = h @ w1^T (split3 MFMA, 16 K-partials)
    gemm_x3<<<dim3(8, 16), dim3(256), 0, stream>>>(
        xh, xm, xl, xh, xm, xl, aw1, aw1, 512, 64, 4, part);
    attn_ctx_k<<<dim3(B), dim3(256), 0, stream>>>(
        part, ab1, aw2, ab2, Sp, hfin, enc, aO, ctxb);

    // fc1: [ctx | out] @ f1w^T -> 16 sequential-staged split-K partials -> tanh
    fc1_gemm<<<dim3(16, 16), dim3(256), 0, stream>>>(ctxb, xh, f1w, part);
    fc1_fin_k<<<dim3(B * H / 256), dim3(256), 0, stream>>>(part, f1b, o2, o2b);

    // fc2: row-sequential staged W -> 2 bf16 K-partials
    fc2_gemm<<<dim3(V / 64, 2), dim3(256), 0, stream>>>(o2b, f2w, pf2);

    // fused fc2-finish (+bias) and log_softmax
    lsm_k<<<dim3(B), dim3(1024), 0, stream>>>(pf2, pf2 + (size_t)B * V, f2b, y);
}